// Round 13
// baseline (151.728 us; speedup 1.0000x reference)
//
#include <hip/hip_runtime.h>
#include <cstdint>

typedef unsigned short u16;
typedef __bf16 bf16x8 __attribute__((ext_vector_type(8)));
typedef float f32x4 __attribute__((ext_vector_type(4)));

#define NB 8192          // batch rows
#define HD 512           // hidden
#define KD 1024          // IN + H
#define ND 2048          // 4H (physical, column-reordered)
#define HY_OFF (NB * HD) // offset of cy in d_out
#define NT 32            // K-tiles of BK=32

// ---------- helpers ----------
__device__ __forceinline__ u16 f2bf(float f) {
  unsigned u = __float_as_uint(f);
  u += 0x7FFFu + ((u >> 16) & 1u);          // round-to-nearest-even bf16
  return (u16)(u >> 16);
}
__device__ __forceinline__ float bf2f(u16 h) {
  return __uint_as_float(((unsigned)h) << 16);
}
__device__ __forceinline__ void atomicMaxF(float* a, float v) {
  if (v >= 0.f) atomicMax((int*)a, __float_as_int(v));
  else          atomicMin((unsigned int*)a, __float_as_uint(v));
}
__device__ __forceinline__ float fq_u(float x) {           // unsigned 8-bit fake-quant
  float xc = fminf(fmaxf(x, 0.0f), 1.0f);
  return rintf(xc * 256.0f) * (1.0f / 256.0f);
}
__device__ __forceinline__ float fq_s(float x) {           // signed 8-bit fake-quant
  const float lim = 1.0f - 1.0f / 128.0f;
  float xc = fminf(fmaxf(x, -lim), lim);
  return rintf(xc * 128.0f) * (1.0f / 128.0f);
}
__device__ __forceinline__ float sigm(float x) { return 1.0f / (1.0f + expf(-x)); }

__device__ __forceinline__ void gload_lds16(const u16* g, u16* l) {
  __builtin_amdgcn_global_load_lds(
      (const __attribute__((address_space(1))) void*)g,
      (__attribute__((address_space(3))) void*)l, 16, 0, 0);
}

// ---------- prep1: split X hi/lo + max reductions (fused) ----------
__global__ __launch_bounds__(256) void k_prep1(
    const float* __restrict__ input, const float* __restrict__ hx,
    const float* __restrict__ w_ih, const float* __restrict__ w_hh,
    const float* __restrict__ b_ih, const float* __restrict__ b_hh,
    u16* __restrict__ Xhi, u16* __restrict__ Xlo, float* __restrict__ maxes) {
  const int bid = blockIdx.x;
  if (bid < 2048) {
    const int total4 = NB * KD / 4;
    for (int e4 = bid * 256 + threadIdx.x; e4 < total4; e4 += 2048 * 256) {
      int row = e4 >> 8;
      int c4  = e4 & 255;
      float4 v = (c4 < 128)
          ? reinterpret_cast<const float4*>(input)[row * 128 + c4]
          : reinterpret_cast<const float4*>(hx)[row * 128 + (c4 - 128)];
      float xs[4] = {v.x, v.y, v.z, v.w};
      ushort4 hi, lo;
      u16 h0 = f2bf(xs[0]); u16 l0 = f2bf(xs[0] - bf2f(h0));
      u16 h1 = f2bf(xs[1]); u16 l1 = f2bf(xs[1] - bf2f(h1));
      u16 h2 = f2bf(xs[2]); u16 l2 = f2bf(xs[2] - bf2f(h2));
      u16 h3 = f2bf(xs[3]); u16 l3 = f2bf(xs[3] - bf2f(h3));
      hi.x = h0; hi.y = h1; hi.z = h2; hi.w = h3;
      lo.x = l0; lo.y = l1; lo.z = l2; lo.w = l3;
      reinterpret_cast<ushort4*>(Xhi)[e4] = hi;
      reinterpret_cast<ushort4*>(Xlo)[e4] = lo;
    }
  } else {
    int mb = bid - 2048;
    const float* src; int slot, base;
    if (mb < 1024)      { src = w_ih; slot = 0; base = mb * 1024; }
    else if (mb < 2048) { src = w_hh; slot = 1; base = (mb - 1024) * 1024; }
    else if (mb < 2050) { src = b_ih; slot = 2; base = (mb - 2048) * 1024; }
    else                { src = b_hh; slot = 3; base = (mb - 2050) * 1024; }
    float m = -INFINITY;
    for (int i = threadIdx.x; i < 1024; i += 256) m = fmaxf(m, src[base + i]);
    for (int k = 1; k < 64; k <<= 1) m = fmaxf(m, __shfl_xor(m, k, 64));
    __shared__ float sm[4];
    if ((threadIdx.x & 63) == 0) sm[threadIdx.x >> 6] = m;
    __syncthreads();
    if (threadIdx.x == 0) {
      m = fmaxf(fmaxf(sm[0], sm[1]), fmaxf(sm[2], sm[3]));
      atomicMaxF(&maxes[slot], m);
    }
  }
}

// ---------- prep2: build W hi/lo (coalesced, LDS transpose) + combined bias ----------
// NEW physical order: j = hb*64 + g*16 + hl  <->  logical col = g*512 + hb*16 + hl
// (hb = j>>6, g = (j>>4)&3, hl = j&15)
__global__ __launch_bounds__(256) void k_prep2(
    const float* __restrict__ w_ih, const float* __restrict__ w_hh,
    const float* __restrict__ n_ih, const float* __restrict__ n_hh,
    const float* __restrict__ b_ih, const float* __restrict__ b_hh,
    const float* __restrict__ nb_ih, const float* __restrict__ nb_hh,
    const float* __restrict__ maxes,
    u16* __restrict__ Whi, u16* __restrict__ Wlo, float* __restrict__ biasC) {
  const int bid = blockIdx.x;
  if (bid < 512) {
    __shared__ float nT[256][17];
    const int cg = bid >> 2, kb = bid & 3;
    const int j0 = cg * 16;
    const int g  = cg & 3;          // (j0>>4)&3
    const int hb = cg >> 2;         // j0>>6
    const int col0 = g * 512 + (hb << 4);
    const int k0 = kb * 256;
    {
      const int cl = threadIdx.x & 15;
      const int kr = threadIdx.x >> 4;
#pragma unroll 4
      for (int i = 0; i < 16; ++i) {
        const int k = k0 + kr + 16 * i;
        nT[kr + 16 * i][cl] = (k < 512) ? n_ih[k * ND + col0 + cl]
                                        : n_hh[(k - 512) * ND + col0 + cl];
      }
    }
    __syncthreads();
    const float s_ih = maxes[0] * 0.1f, s_hh = maxes[1] * 0.1f;
    const int c  = threadIdx.x >> 4;
    const int kl = threadIdx.x & 15;
    const int colL = col0 + c;
    const int j = j0 + c;
#pragma unroll
    for (int kk = 0; kk < 4; ++kk) {
      const int k = k0 + kk * 64 + kl * 4;
      float4 wv; float s;
      if (k < 512) {
        wv = reinterpret_cast<const float4*>(w_ih)[(colL * 512 + k) >> 2];
        s = s_ih;
      } else {
        wv = reinterpret_cast<const float4*>(w_hh)[(colL * 512 + k - 512) >> 2];
        s = s_hh;
      }
      const int kt = k - k0;
      float xs[4] = {wv.x + nT[kt + 0][c] * s, wv.y + nT[kt + 1][c] * s,
                     wv.z + nT[kt + 2][c] * s, wv.w + nT[kt + 3][c] * s};
      ushort4 hi, lo;
      u16 h0 = f2bf(xs[0]); u16 l0 = f2bf(xs[0] - bf2f(h0));
      u16 h1 = f2bf(xs[1]); u16 l1 = f2bf(xs[1] - bf2f(h1));
      u16 h2 = f2bf(xs[2]); u16 l2 = f2bf(xs[2] - bf2f(h2));
      u16 h3 = f2bf(xs[3]); u16 l3 = f2bf(xs[3] - bf2f(h3));
      hi.x = h0; hi.y = h1; hi.z = h2; hi.w = h3;
      lo.x = l0; lo.y = l1; lo.z = l2; lo.w = l3;
      reinterpret_cast<ushort4*>(Whi)[(j * KD + k) >> 2] = hi;
      reinterpret_cast<ushort4*>(Wlo)[(j * KD + k) >> 2] = lo;
    }
  } else {
    int j = (bid - 512) * 256 + threadIdx.x;
    if (j < ND) {
      int hb = j >> 6, g = (j >> 4) & 3, hl = j & 15;
      int col = g * 512 + (hb << 4) + hl;
      biasC[j] = b_ih[col] + nb_ih[col] * (maxes[2] * 0.1f)
               + b_hh[col] + nb_hh[col] * (maxes[3] * 0.1f);
    }
  }
}

// ---------- GEMM 128x128-tile, BK=32 unified, 2 blocks/CU ----------
// grid 1024 = 64 bm x 16 bn; 256 threads (4 waves, 2x2); LDS 64 KiB =
// 2 slots x 4 bufs (Ahi,Alo,Bhi,Blo) x 128x32 bf16. 2 blocks resident/CU ->
// each SIMD hosts waves from TWO independent (non-barrier-synced) blocks:
// one block's stall is covered by the other's MFMA stream.
// Per tile: 2 barriers + 1 counted vmcnt(2). Stages for tile U+1 go to the
// OTHER slot (no intra-tile WAR); ph0's vmcnt(2)+barrier validates tile U
// (all 8 loads issued one full tile earlier); trailing barrier fences this
// tile's reads (auto-lgkm'd before their MFMAs) before next tile's stages.
__global__ __launch_bounds__(256, 2) void k_gemm_lstm(
    const u16* __restrict__ Xhi, const u16* __restrict__ Xlo,
    const u16* __restrict__ Whi, const u16* __restrict__ Wlo,
    const float* __restrict__ biasC, const float* __restrict__ cx,
    float* __restrict__ out) {
  __shared__ u16 L[2][4][4096];   // [slot][buf][128 rows x 32 u16, pair-row layout]
  const int tid  = threadIdx.x;
  const int lane = tid & 63, wid = tid >> 6;
  const int wr = wid >> 1, wc = wid & 1;       // 2 x 2 waves
  const int lr = lane & 15, lg = lane >> 4;
  const int l7 = lane & 7, l8 = lane >> 3;
  // XCD map: xcd owns an 8bm x 16bn region; within: bm fast (8 blocks share B)
  const int xcd = blockIdx.x & 7, tt = blockIdx.x >> 3;
  const int bm = xcd * 8 + (tt & 7);   // 0..63
  const int bn = tt >> 3;              // 0..15
  const int mbase = bm * 128, nbase = bn * 128;

  // staging consts (identical pattern to r3, proven conflict-free):
  const int csrc  = l7 ^ l8;
  const int srow  = wid * 16 + 2 * l8 + (csrc >> 2);  // row within 64-row half
  const int skoff = (csrc & 3) * 8;                   // k offset (u16)
  const int sdst  = wid * 512;                        // + HALF*2048 (u16)

  // frag-read swizzled offset (u16): pair-row + chunk XOR (r3 formula)
  const int fro = (lr >> 1) * 64 + ((((lr & 1) << 2) | lg) ^ ((lr >> 1) & 7)) * 8;

  f32x4 acc[4][4] = {};     // [m2][gate = n2]
  bf16x8 afr[4][2];         // [m2][hi/lo], read once per tile at ph0
  bf16x8 bfrp[2];           // current-phase B frag (hi,lo)

#define STAGE(V, SLOT, BUF, HALF)                                             \
  {                                                                           \
    const u16* arr_ = (BUF) == 0 ? Xhi : (BUF) == 1 ? Xlo                     \
                      : (BUF) == 2 ? Whi : Wlo;                               \
    const int gb_ = ((BUF) < 2 ? mbase : nbase) + (HALF) * 64 + srow;         \
    gload_lds16(arr_ + (size_t)gb_ * KD + (V) * 32 + skoff,                   \
                &L[(SLOT)][(BUF)][(HALF) * 2048 + sdst]);                     \
  }

#define MMPH(S, N2)                                                           \
  {                                                                           \
    const int bb_ = (wc * 64 + (N2) * 16) * 32 + fro;                         \
    bfrp[0] = *reinterpret_cast<const bf16x8*>(&L[S][2][bb_]);                \
    bfrp[1] = *reinterpret_cast<const bf16x8*>(&L[S][3][bb_]);                \
    __builtin_amdgcn_s_setprio(1);                                            \
    _Pragma("unroll") for (int t = 0; t < 3; ++t)                             \
      _Pragma("unroll") for (int m2 = 0; m2 < 4; ++m2) {                      \
        f32x4* ac = &acc[m2][N2];                                             \
        *ac = __builtin_amdgcn_mfma_f32_16x16x32_bf16(afr[m2][t == 1],        \
                  bfrp[t == 2], *ac, 0, 0, 0);                                \
      }                                                                       \
    __builtin_amdgcn_s_setprio(0);                                            \
  }

#define TILE(U, S)                                                            \
  {                                                                           \
    const int Vn = ((U) + 1 > NT - 1) ? (NT - 1) : (U) + 1;                   \
    STAGE(Vn, (S) ^ 1, 0, 0); STAGE(Vn, (S) ^ 1, 0, 1);                       \
    asm volatile("s_waitcnt vmcnt(2)" ::: "memory");                          \
    __builtin_amdgcn_s_barrier();                                             \
    _Pragma("unroll") for (int m2 = 0; m2 < 4; ++m2) {                        \
      const int ab_ = (wr * 64 + m2 * 16) * 32 + fro;                         \
      afr[m2][0] = *reinterpret_cast<const bf16x8*>(&L[S][0][ab_]);           \
      afr[m2][1] = *reinterpret_cast<const bf16x8*>(&L[S][1][ab_]);           \
    }                                                                         \
    MMPH(S, 0)                                                                \
    STAGE(Vn, (S) ^ 1, 1, 0); STAGE(Vn, (S) ^ 1, 1, 1);                       \
    MMPH(S, 1)                                                                \
    STAGE(Vn, (S) ^ 1, 2, 0); STAGE(Vn, (S) ^ 1, 2, 1);                       \
    MMPH(S, 2)                                                                \
    STAGE(Vn, (S) ^ 1, 3, 0); STAGE(Vn, (S) ^ 1, 3, 1);                       \
    MMPH(S, 3)                                                                \
    __builtin_amdgcn_s_barrier();                                             \
  }

  // prologue: stage tile 0 into slot 0 (8 gloads); loop ph0's vmcnt(2) drains it
  STAGE(0, 0, 0, 0); STAGE(0, 0, 0, 1);
  STAGE(0, 0, 1, 0); STAGE(0, 0, 1, 1);
  STAGE(0, 0, 2, 0); STAGE(0, 0, 2, 1);
  STAGE(0, 0, 3, 0); STAGE(0, 0, 3, 1);

  for (int u = 0; u < NT; u += 2) {
    TILE(u, 0)
    TILE(u + 1, 1)
  }

#undef TILE
#undef MMPH
#undef STAGE

  // ---------- fused quantized-LSTM epilogue (fully wave-local) ----------
  const int hb = bn * 2 + wc;
  const int h = hb * 16 + lr;
  float bias[4];
#pragma unroll
  for (int g = 0; g < 4; ++g) bias[g] = biasC[hb * 64 + g * 16 + lr];
#pragma unroll
  for (int m2 = 0; m2 < 4; ++m2) {
#pragma unroll
    for (int r = 0; r < 4; ++r) {
      const int row = mbase + wr * 64 + m2 * 16 + lg * 4 + r;
      const float gi = acc[m2][0][r] + bias[0];
      const float gf = acc[m2][1][r] + bias[1];
      const float gc = acc[m2][2][r] + bias[2];
      const float go = acc[m2][3][r] + bias[3];
      const float ig = fq_u(sigm(gi));
      const float fg = fq_u(sigm(gf));
      const float cg = fq_s(tanhf(gc));
      const float og = fq_u(sigm(go));
      const float cxv = cx[(size_t)row * HD + h];
      const float t1 = fq_s(fg * cxv);
      const float t2 = fq_s(ig * cg);
      const float cyv = fq_s((t1 + t2) * 0.5f);
      const float hyv = fq_s(og * fq_s(tanhf(cyv * 2.0f)));
      out[(size_t)row * HD + h] = hyv;
      out[HY_OFF + (size_t)row * HD + h] = cyv;
    }
  }
}

// ---------- launch ----------
extern "C" void kernel_launch(void* const* d_in, const int* in_sizes, int n_in,
                              void* d_out, int out_size, void* d_ws, size_t ws_size,
                              hipStream_t stream) {
  const float* input = (const float*)d_in[0];
  const float* hx    = (const float*)d_in[1];
  const float* cx    = (const float*)d_in[2];
  const float* w_ih  = (const float*)d_in[3];
  const float* w_hh  = (const float*)d_in[4];
  const float* b_ih  = (const float*)d_in[5];
  const float* b_hh  = (const float*)d_in[6];
  const float* n_ih  = (const float*)d_in[7];
  const float* n_hh  = (const float*)d_in[8];
  const float* nb_ih = (const float*)d_in[9];
  const float* nb_hh = (const float*)d_in[10];
  float* out = (float*)d_out;

  char* ws = (char*)d_ws;
  float* maxes = (float*)ws;                                   // 16 B (+pad to 256)
  u16* Xhi = (u16*)(ws + 256);                                 // 16 MB
  u16* Xlo = (u16*)(ws + 256 + 16777216);                      // 16 MB
  u16* Whi = (u16*)(ws + 256 + 2 * 16777216);                  // 4 MB
  u16* Wlo = (u16*)(ws + 256 + 2 * 16777216 + 4194304);        // 4 MB
  float* biasC = (float*)(ws + 256 + 2 * 16777216 + 2 * 4194304); // 8 KB

  hipMemsetAsync(maxes, 0xFF, 16, stream);  // -NaN sentinel; atomic lattice fixes it
  hipLaunchKernelGGL(k_prep1, dim3(4100), dim3(256), 0, stream,
                     input, hx, w_ih, w_hh, b_ih, b_hh, Xhi, Xlo, maxes);
  hipLaunchKernelGGL(k_prep2, dim3(520), dim3(256), 0, stream,
                     w_ih, w_hh, n_ih, n_hh, b_ih, b_hh, nb_ih, nb_hh,
                     maxes, Whi, Wlo, biasC);
  hipLaunchKernelGGL(k_gemm_lstm, dim3(1024), dim3(256), 0, stream,
                     Xhi, Xlo, Whi, Wlo, biasC, cx, out);
}

// Round 14
// 124.109 us; speedup vs baseline: 1.2225x; 1.2225x over previous
//
#include <hip/hip_runtime.h>
#include <cstdint>

typedef unsigned short u16;
typedef __bf16 bf16x8 __attribute__((ext_vector_type(8)));
typedef float f32x4 __attribute__((ext_vector_type(4)));

#define NB 8192          // batch rows
#define HD 512           // hidden
#define KD 1024          // IN + H
#define ND 2048          // 4H (physical, column-reordered)
#define HY_OFF (NB * HD) // offset of cy in d_out
#define NT 32            // K-tiles of BK=32

// ---------- helpers ----------
__device__ __forceinline__ u16 f2bf(float f) {
  unsigned u = __float_as_uint(f);
  u += 0x7FFFu + ((u >> 16) & 1u);          // round-to-nearest-even bf16
  return (u16)(u >> 16);
}
__device__ __forceinline__ float bf2f(u16 h) {
  return __uint_as_float(((unsigned)h) << 16);
}
__device__ __forceinline__ void atomicMaxF(float* a, float v) {
  if (v >= 0.f) atomicMax((int*)a, __float_as_int(v));
  else          atomicMin((unsigned int*)a, __float_as_uint(v));
}
__device__ __forceinline__ float fq_u(float x) {           // unsigned 8-bit fake-quant
  float xc = fminf(fmaxf(x, 0.0f), 1.0f);
  return rintf(xc * 256.0f) * (1.0f / 256.0f);
}
__device__ __forceinline__ float fq_s(float x) {           // signed 8-bit fake-quant
  const float lim = 1.0f - 1.0f / 128.0f;
  float xc = fminf(fmaxf(x, -lim), lim);
  return rintf(xc * 128.0f) * (1.0f / 128.0f);
}
__device__ __forceinline__ float sigm(float x) { return 1.0f / (1.0f + expf(-x)); }

__device__ __forceinline__ void gload_lds16(const u16* g, u16* l) {
  __builtin_amdgcn_global_load_lds(
      (const __attribute__((address_space(1))) void*)g,
      (__attribute__((address_space(3))) void*)l, 16, 0, 0);
}

// ---------- k_max: minimal max-reduce (float4) ----------
// blocks [0,256): w_ih ; [256,512): w_hh ; 512: b_ih ; 513: b_hh
__global__ __launch_bounds__(256) void k_max(
    const float* __restrict__ w_ih, const float* __restrict__ w_hh,
    const float* __restrict__ b_ih, const float* __restrict__ b_hh,
    float* __restrict__ maxes) {
  const int bid = blockIdx.x;
  const float4* src; int slot, base4, n4;
  if (bid < 256)      { src = (const float4*)w_ih; slot = 0; base4 = bid * 1024; n4 = 1024; }
  else if (bid < 512) { src = (const float4*)w_hh; slot = 1; base4 = (bid - 256) * 1024; n4 = 1024; }
  else if (bid == 512){ src = (const float4*)b_ih; slot = 2; base4 = 0; n4 = 512; }
  else                { src = (const float4*)b_hh; slot = 3; base4 = 0; n4 = 512; }
  float m = -INFINITY;
  for (int i = threadIdx.x; i < n4; i += 256) {
    float4 v = src[base4 + i];
    m = fmaxf(m, fmaxf(fmaxf(v.x, v.y), fmaxf(v.z, v.w)));
  }
  for (int k = 1; k < 64; k <<= 1) m = fmaxf(m, __shfl_xor(m, k, 64));
  __shared__ float sm[4];
  if ((threadIdx.x & 63) == 0) sm[threadIdx.x >> 6] = m;
  __syncthreads();
  if (threadIdx.x == 0) {
    m = fmaxf(fmaxf(sm[0], sm[1]), fmaxf(sm[2], sm[3]));
    atomicMaxF(&maxes[slot], m);
  }
}

// ---------- fused prep: split X hi/lo + build W hi/lo (coalesced) + bias ----------
// blocks [0,2048): split X ; [2048,2560): W (16 cols x 256 k each) ; [2560,2568): bias
// W physical j bits: [10:8]=bn, [7]=nh, [6:5]=wc, [4]=n2, [3:0]=lane
// gate g = 2*nh + n2 ; h-block hb = bn*4 + wc ; logical col = g*512 + hb*16 + j[3:0]
__global__ __launch_bounds__(256) void k_prep(
    const float* __restrict__ input, const float* __restrict__ hx,
    const float* __restrict__ w_ih, const float* __restrict__ w_hh,
    const float* __restrict__ n_ih, const float* __restrict__ n_hh,
    const float* __restrict__ b_ih, const float* __restrict__ b_hh,
    const float* __restrict__ nb_ih, const float* __restrict__ nb_hh,
    const float* __restrict__ maxes,
    u16* __restrict__ Xhi, u16* __restrict__ Xlo,
    u16* __restrict__ Whi, u16* __restrict__ Wlo,
    float* __restrict__ biasC) {
  const int bid = blockIdx.x;
  if (bid < 2048) {
    const int total4 = NB * KD / 4;
    for (int e4 = bid * 256 + threadIdx.x; e4 < total4; e4 += 2048 * 256) {
      int row = e4 >> 8;
      int c4  = e4 & 255;
      float4 v = (c4 < 128)
          ? reinterpret_cast<const float4*>(input)[row * 128 + c4]
          : reinterpret_cast<const float4*>(hx)[row * 128 + (c4 - 128)];
      float xs[4] = {v.x, v.y, v.z, v.w};
      ushort4 hi, lo;
      u16 h0 = f2bf(xs[0]); u16 l0 = f2bf(xs[0] - bf2f(h0));
      u16 h1 = f2bf(xs[1]); u16 l1 = f2bf(xs[1] - bf2f(h1));
      u16 h2 = f2bf(xs[2]); u16 l2 = f2bf(xs[2] - bf2f(h2));
      u16 h3 = f2bf(xs[3]); u16 l3 = f2bf(xs[3] - bf2f(h3));
      hi.x = h0; hi.y = h1; hi.z = h2; hi.w = h3;
      lo.x = l0; lo.y = l1; lo.z = l2; lo.w = l3;
      reinterpret_cast<ushort4*>(Xhi)[e4] = hi;
      reinterpret_cast<ushort4*>(Xlo)[e4] = lo;
    }
  } else if (bid < 2560) {
    // one block: 16 physical cols (one lane-group) x 256 k-rows
    __shared__ float nT[256][17];   // padded transpose buffer (17 KB)
    const int w  = bid - 2048;      // 0..511
    const int cg = w >> 2, kb = w & 3;
    const int j0 = cg * 16;
    const int g  = ((j0 >> 7) & 1) * 2 + ((j0 >> 4) & 1);
    const int hb = ((j0 >> 8) << 2) | ((j0 >> 5) & 3);
    const int col0 = g * 512 + (hb << 4);
    const int k0 = kb * 256;
    {  // stage noise[k0..k0+256)[col0..col0+16) -> nT, coalesced
      const int cl = threadIdx.x & 15;
      const int kr = threadIdx.x >> 4;
#pragma unroll 4
      for (int i = 0; i < 16; ++i) {
        const int k = k0 + kr + 16 * i;
        nT[kr + 16 * i][cl] = (k < 512) ? n_ih[k * ND + col0 + cl]
                                        : n_hh[(k - 512) * ND + col0 + cl];
      }
    }
    __syncthreads();
    const float s_ih = maxes[0] * 0.1f, s_hh = maxes[1] * 0.1f;
    const int c  = threadIdx.x >> 4;       // col 0..15
    const int kl = threadIdx.x & 15;
    const int colL = col0 + c;
    const int j = j0 + c;
#pragma unroll
    for (int kk = 0; kk < 4; ++kk) {
      const int k = k0 + kk * 64 + kl * 4;
      float4 wv; float s;
      if (k < 512) {
        wv = reinterpret_cast<const float4*>(w_ih)[(colL * 512 + k) >> 2];
        s = s_ih;
      } else {
        wv = reinterpret_cast<const float4*>(w_hh)[(colL * 512 + k - 512) >> 2];
        s = s_hh;
      }
      const int kt = k - k0;
      float xs[4] = {wv.x + nT[kt + 0][c] * s, wv.y + nT[kt + 1][c] * s,
                     wv.z + nT[kt + 2][c] * s, wv.w + nT[kt + 3][c] * s};
      ushort4 hi, lo;
      u16 h0 = f2bf(xs[0]); u16 l0 = f2bf(xs[0] - bf2f(h0));
      u16 h1 = f2bf(xs[1]); u16 l1 = f2bf(xs[1] - bf2f(h1));
      u16 h2 = f2bf(xs[2]); u16 l2 = f2bf(xs[2] - bf2f(h2));
      u16 h3 = f2bf(xs[3]); u16 l3 = f2bf(xs[3] - bf2f(h3));
      hi.x = h0; hi.y = h1; hi.z = h2; hi.w = h3;
      lo.x = l0; lo.y = l1; lo.z = l2; lo.w = l3;
      reinterpret_cast<ushort4*>(Whi)[(j * KD + k) >> 2] = hi;
      reinterpret_cast<ushort4*>(Wlo)[(j * KD + k) >> 2] = lo;
    }
  } else {
    int j = (bid - 2560) * 256 + threadIdx.x;
    if (j < ND) {
      int g  = ((j >> 7) & 1) * 2 + ((j >> 4) & 1);
      int hb = ((j >> 8) << 2) | ((j >> 5) & 3);
      int col = g * 512 + (hb << 4) + (j & 15);
      biasC[j] = b_ih[col] + nb_ih[col] * (maxes[2] * 0.1f)
               + b_hh[col] + nb_hh[col] * (maxes[3] * 0.1f);
    }
  }
}

// ---------- GEMM 256x256-tile, BK=32 unified (r3 verbatim -- best measured) ----------
// grid 256; 512 threads (8 waves, 2x4); LDS 128 KiB = 2 slots x 4 bufs x 16 KB.
// Per K=32 tile: 4 phases x 24 MFMA (3 terms: hihi + lohi + hilo).
__global__ __launch_bounds__(512, 2) void k_gemm_lstm(
    const u16* __restrict__ Xhi, const u16* __restrict__ Xlo,
    const u16* __restrict__ Whi, const u16* __restrict__ Wlo,
    const float* __restrict__ biasC, const float* __restrict__ cx,
    float* __restrict__ out) {
  __shared__ u16 L[2][4][8192];   // [slot][Ahi,Alo,Bhi,Blo][128x64]
  const int tid  = threadIdx.x;
  const int lane = tid & 63, wid = tid >> 6;
  const int wr = wid >> 2, wc = wid & 3;       // 2 x 4 waves
  const int lr = lane & 15, lg = lane >> 4;
  // XCD-region map: xcd = blk%8 owns an 8bm x 4bn region (bijective)
  const int xcd = blockIdx.x & 7, tt = blockIdx.x >> 3;
  const int bm = ((xcd >> 1) << 3) | (tt & 7);   // 0..31
  const int bn = ((xcd & 1) << 2) | (tt >> 3);   // 0..7
  const int mbase = bm * 256, nbase = bn * 256;

  // staging consts: lane l -> ldsrow (l>>3), lds chunk l&7, src chunk (l&7)^(l>>3)
  const int l8 = lane >> 3, l7 = lane & 7;
  const int csrc  = l7 ^ l8;
  const int srow  = wid * 16 + 2 * l8 + (csrc >> 2);  // global row offset in panel
  const int skoff = (csrc & 3) * 8;                   // k offset (u16)
  const int sdst  = wid * 512;                        // + HALF*4096 (u16)

  // frag-read per-thread swizzled offset (u16): row pair + chunk XOR
  const int fro = (lr >> 1) * 64 + ((((lr & 1) << 2) | lg) ^ ((lr >> 1) & 7)) * 8;

  f32x4 acc[8][4] = {};     // [mh*4+m2][gate = 2*nh+n2]
  bf16x8 afr[4][2];         // [m2][hi/lo]
  bf16x8 bfr[2][2][2];      // [nh][n2][hi/lo]

#define STAGE(V, BUF, HALF)                                                   \
  {                                                                           \
    const u16* arr_ = (BUF) == 0 ? Xhi : (BUF) == 1 ? Xlo                     \
                      : (BUF) == 2 ? Whi : Wlo;                               \
    const int gb_ = ((BUF) < 2 ? mbase : nbase) + (HALF) * 128 + srow;        \
    gload_lds16(arr_ + (size_t)gb_ * KD + (V) * 32 + skoff,                   \
                &L[(V) & 1][(BUF)][(HALF) * 4096 + sdst]);                    \
  }

#define PH(MH, NH, LOADA, LOADB, STAGE_CODE, WAIT_CODE)                       \
  {                                                                           \
    if (LOADA) {                                                              \
      _Pragma("unroll") for (int m2 = 0; m2 < 4; ++m2) {                      \
        const int ab = ((MH) * 128 + wr * 64 + m2 * 16) * 32 + fro;           \
        afr[m2][0] = *reinterpret_cast<const bf16x8*>(&L[s][0][ab]);          \
        afr[m2][1] = *reinterpret_cast<const bf16x8*>(&L[s][1][ab]);          \
      }                                                                       \
    }                                                                         \
    if (LOADB) {                                                              \
      _Pragma("unroll") for (int n2 = 0; n2 < 2; ++n2) {                      \
        const int bb = ((NH) * 128 + wc * 32 + n2 * 16) * 32 + fro;           \
        bfr[(NH)][n2][0] = *reinterpret_cast<const bf16x8*>(&L[s][2][bb]);    \
        bfr[(NH)][n2][1] = *reinterpret_cast<const bf16x8*>(&L[s][3][bb]);    \
      }                                                                       \
    }                                                                         \
    STAGE_CODE;                                                               \
    WAIT_CODE;                                                                \
    __builtin_amdgcn_s_barrier();                                             \
    __builtin_amdgcn_s_setprio(1);                                            \
    _Pragma("unroll") for (int t = 0; t < 3; ++t)                             \
      _Pragma("unroll") for (int m2 = 0; m2 < 4; ++m2)                        \
        _Pragma("unroll") for (int n2 = 0; n2 < 2; ++n2) {                    \
          f32x4* ac = &acc[(MH) * 4 + m2][(NH) * 2 + n2];                     \
          *ac = __builtin_amdgcn_mfma_f32_16x16x32_bf16(afr[m2][t == 1],      \
                    bfr[(NH)][n2][t == 2], *ac, 0, 0, 0);                     \
        }                                                                     \
    __builtin_amdgcn_s_setprio(0);                                            \
    __builtin_amdgcn_s_barrier();                                             \
  }

  // prologue: stage tile 0 in consumption order P1..P8
  STAGE(0, 0, 0); STAGE(0, 1, 0);   // Ahi.h0, Alo.h0
  STAGE(0, 2, 0); STAGE(0, 3, 0);   // Bhi.h0, Blo.h0
  STAGE(0, 2, 1); STAGE(0, 3, 1);   // Bhi.h1, Blo.h1
  STAGE(0, 0, 1); STAGE(0, 1, 1);   // Ahi.h1, Alo.h1
  asm volatile("s_waitcnt vmcnt(4)" ::: "memory");   // P1..P4 landed
  __builtin_amdgcn_s_barrier();

  int s = 0;
  for (int u = 0; u < NT - 1; ++u, s ^= 1) {
    // ph0 (mh0,nh0): reads P1..P4 data; stage N1,N2; wait -> P5,P6 for ph1
    PH(0, 0, 1, 1, { STAGE(u + 1, 0, 0); STAGE(u + 1, 1, 0); },
       asm volatile("s_waitcnt vmcnt(4)" ::: "memory"));
    // ph1 (mh0,nh1): reads P5,P6; stage N3,N4; wait -> P7,P8 for ph2
    PH(0, 1, 0, 1, { STAGE(u + 1, 2, 0); STAGE(u + 1, 3, 0); },
       asm volatile("s_waitcnt vmcnt(4)" ::: "memory"));
    // ph2 (mh1,nh1): reads P7,P8; stage N5,N6; no wait
    PH(1, 1, 1, 0, { STAGE(u + 1, 2, 1); STAGE(u + 1, 3, 1); }, );
    // ph3 (mh1,nh0): no reads; stage N7,N8; wait -> N1..N4 for next ph0
    PH(1, 0, 0, 0, { STAGE(u + 1, 0, 1); STAGE(u + 1, 1, 1); },
       asm volatile("s_waitcnt vmcnt(4)" ::: "memory"));
  }
  // peeled tile NT-1 (s == 1): no staging; drain
  PH(0, 0, 1, 1, , asm volatile("s_waitcnt vmcnt(2)" ::: "memory"));
  PH(0, 1, 0, 1, , asm volatile("s_waitcnt vmcnt(0)" ::: "memory"));
  PH(1, 1, 1, 0, , );
  PH(1, 0, 0, 0, , );

#undef PH
#undef STAGE

  // ---------- fused quantized-LSTM epilogue ----------
  const int hb = bn * 4 + wc;
  const int h = hb * 16 + lr;
  float bias[4];
#pragma unroll
  for (int g = 0; g < 4; ++g)
    bias[g] = biasC[bn * 256 + ((g >> 1) * 8 + wc * 2 + (g & 1)) * 16 + lr];
#pragma unroll
  for (int mh = 0; mh < 2; ++mh) {
#pragma unroll
    for (int m2 = 0; m2 < 4; ++m2) {
      const int m = mh * 4 + m2;
#pragma unroll
      for (int r = 0; r < 4; ++r) {
        const int row = mbase + mh * 128 + wr * 64 + m2 * 16 + lg * 4 + r;
        const float gi = acc[m][0][r] + bias[0];
        const float gf = acc[m][1][r] + bias[1];
        const float gc = acc[m][2][r] + bias[2];
        const float go = acc[m][3][r] + bias[3];
        const float ig = fq_u(sigm(gi));
        const float fg = fq_u(sigm(gf));
        const float cg = fq_s(tanhf(gc));
        const float og = fq_u(sigm(go));
        const float cxv = cx[(size_t)row * HD + h];
        const float t1 = fq_s(fg * cxv);
        const float t2 = fq_s(ig * cg);
        const float cyv = fq_s((t1 + t2) * 0.5f);
        const float hyv = fq_s(og * fq_s(tanhf(cyv * 2.0f)));
        out[(size_t)row * HD + h] = hyv;
        out[HY_OFF + (size_t)row * HD + h] = cyv;
      }
    }
  }
}

// ---------- launch ----------
extern "C" void kernel_launch(void* const* d_in, const int* in_sizes, int n_in,
                              void* d_out, int out_size, void* d_ws, size_t ws_size,
                              hipStream_t stream) {
  const float* input = (const float*)d_in[0];
  const float* hx    = (const float*)d_in[1];
  const float* cx    = (const float*)d_in[2];
  const float* w_ih  = (const float*)d_in[3];
  const float* w_hh  = (const float*)d_in[4];
  const float* b_ih  = (const float*)d_in[5];
  const float* b_hh  = (const float*)d_in[6];
  const float* n_ih  = (const float*)d_in[7];
  const float* n_hh  = (const float*)d_in[8];
  const float* nb_ih = (const float*)d_in[9];
  const float* nb_hh = (const float*)d_in[10];
  float* out = (float*)d_out;

  char* ws = (char*)d_ws;
  float* maxes = (float*)ws;                                   // 16 B (+pad to 256)
  u16* Xhi = (u16*)(ws + 256);                                 // 16 MB
  u16* Xlo = (u16*)(ws + 256 + 16777216);                      // 16 MB
  u16* Whi = (u16*)(ws + 256 + 2 * 16777216);                  // 4 MB
  u16* Wlo = (u16*)(ws + 256 + 2 * 16777216 + 4194304);        // 4 MB
  float* biasC = (float*)(ws + 256 + 2 * 16777216 + 2 * 4194304); // 8 KB

  hipMemsetAsync(maxes, 0xFF, 16, stream);  // -NaN sentinel; atomic lattice fixes it
  hipLaunchKernelGGL(k_max, dim3(514), dim3(256), 0, stream,
                     w_ih, w_hh, b_ih, b_hh, maxes);
  hipLaunchKernelGGL(k_prep, dim3(2568), dim3(256), 0, stream,
                     input, hx, w_ih, w_hh, n_ih, n_hh, b_ih, b_hh,
                     nb_ih, nb_hh, maxes, Xhi, Xlo, Whi, Wlo, biasC);
  hipLaunchKernelGGL(k_gemm_lstm, dim3(256), dim3(512), 0, stream,
                     Xhi, Xlo, Whi, Wlo, biasC, cx, out);
}

// Round 15
// 123.873 us; speedup vs baseline: 1.2249x; 1.0019x over previous
//
#include <hip/hip_runtime.h>
#include <cstdint>

typedef unsigned short u16;
typedef __bf16 bf16x8 __attribute__((ext_vector_type(8)));
typedef float f32x4 __attribute__((ext_vector_type(4)));

#define NB 8192          // batch rows
#define HD 512           // hidden
#define KD 1024          // IN + H
#define ND 2048          // 4H (physical, column-reordered)
#define HY_OFF (NB * HD) // offset of cy in d_out
#define NT 32            // K-tiles of BK=32

// ---------- helpers ----------
__device__ __forceinline__ u16 f2bf(float f) {
  unsigned u = __float_as_uint(f);
  u += 0x7FFFu + ((u >> 16) & 1u);          // round-to-nearest-even bf16
  return (u16)(u >> 16);
}
__device__ __forceinline__ float bf2f(u16 h) {
  return __uint_as_float(((unsigned)h) << 16);
}
__device__ __forceinline__ void atomicMaxF(float* a, float v) {
  if (v >= 0.f) atomicMax((int*)a, __float_as_int(v));
  else          atomicMin((unsigned int*)a, __float_as_uint(v));
}
__device__ __forceinline__ float fq_u(float x) {           // unsigned 8-bit fake-quant
  float xc = fminf(fmaxf(x, 0.0f), 1.0f);
  return rintf(xc * 256.0f) * (1.0f / 256.0f);
}
__device__ __forceinline__ float fq_s(float x) {           // signed 8-bit fake-quant
  const float lim = 1.0f - 1.0f / 128.0f;
  float xc = fminf(fmaxf(x, -lim), lim);
  return rintf(xc * 128.0f) * (1.0f / 128.0f);
}
__device__ __forceinline__ float sigm(float x) { return 1.0f / (1.0f + expf(-x)); }

__device__ __forceinline__ void gload_lds16(const u16* g, u16* l) {
  __builtin_amdgcn_global_load_lds(
      (const __attribute__((address_space(1))) void*)g,
      (__attribute__((address_space(3))) void*)l, 16, 0, 0);
}

// ---------- k_max: minimal max-reduce (float4) ----------
// blocks [0,256): w_ih ; [256,512): w_hh ; 512: b_ih ; 513: b_hh
__global__ __launch_bounds__(256) void k_max(
    const float* __restrict__ w_ih, const float* __restrict__ w_hh,
    const float* __restrict__ b_ih, const float* __restrict__ b_hh,
    float* __restrict__ maxes) {
  const int bid = blockIdx.x;
  const float4* src; int slot, base4, n4;
  if (bid < 256)      { src = (const float4*)w_ih; slot = 0; base4 = bid * 1024; n4 = 1024; }
  else if (bid < 512) { src = (const float4*)w_hh; slot = 1; base4 = (bid - 256) * 1024; n4 = 1024; }
  else if (bid == 512){ src = (const float4*)b_ih; slot = 2; base4 = 0; n4 = 512; }
  else                { src = (const float4*)b_hh; slot = 3; base4 = 0; n4 = 512; }
  float m = -INFINITY;
  for (int i = threadIdx.x; i < n4; i += 256) {
    float4 v = src[base4 + i];
    m = fmaxf(m, fmaxf(fmaxf(v.x, v.y), fmaxf(v.z, v.w)));
  }
  for (int k = 1; k < 64; k <<= 1) m = fmaxf(m, __shfl_xor(m, k, 64));
  __shared__ float sm[4];
  if ((threadIdx.x & 63) == 0) sm[threadIdx.x >> 6] = m;
  __syncthreads();
  if (threadIdx.x == 0) {
    m = fmaxf(fmaxf(sm[0], sm[1]), fmaxf(sm[2], sm[3]));
    atomicMaxF(&maxes[slot], m);
  }
}

// ---------- fused prep: W-build FIRST (overlaps X-split), then bias, then X ----------
// blocks [0,512): W (16 cols x 256 k each) ; [512,520): bias ; [520,2568): split X
// W physical j bits: [10:8]=bn, [7]=nh, [6:5]=wc, [4]=n2, [3:0]=lane
// gate g = 2*nh + n2 ; h-block hb = bn*4 + wc ; logical col = g*512 + hb*16 + j[3:0]
__global__ __launch_bounds__(256) void k_prep(
    const float* __restrict__ input, const float* __restrict__ hx,
    const float* __restrict__ w_ih, const float* __restrict__ w_hh,
    const float* __restrict__ n_ih, const float* __restrict__ n_hh,
    const float* __restrict__ b_ih, const float* __restrict__ b_hh,
    const float* __restrict__ nb_ih, const float* __restrict__ nb_hh,
    const float* __restrict__ maxes,
    u16* __restrict__ Xhi, u16* __restrict__ Xlo,
    u16* __restrict__ Whi, u16* __restrict__ Wlo,
    float* __restrict__ biasC) {
  const int bid = blockIdx.x;
  if (bid < 512) {
    // one block: 16 physical cols (one lane-group) x 256 k-rows
    __shared__ float nT[256][17];   // padded transpose buffer (17 KB)
    const int cg = bid >> 2, kb = bid & 3;
    const int j0 = cg * 16;
    const int g  = ((j0 >> 7) & 1) * 2 + ((j0 >> 4) & 1);
    const int hb = ((j0 >> 8) << 2) | ((j0 >> 5) & 3);
    const int col0 = g * 512 + (hb << 4);
    const int k0 = kb * 256;
    {  // stage noise[k0..k0+256)[col0..col0+16) -> nT, coalesced
      const int cl = threadIdx.x & 15;
      const int kr = threadIdx.x >> 4;
#pragma unroll 4
      for (int i = 0; i < 16; ++i) {
        const int k = k0 + kr + 16 * i;
        nT[kr + 16 * i][cl] = (k < 512) ? n_ih[k * ND + col0 + cl]
                                        : n_hh[(k - 512) * ND + col0 + cl];
      }
    }
    __syncthreads();
    const float s_ih = maxes[0] * 0.1f, s_hh = maxes[1] * 0.1f;
    const int c  = threadIdx.x >> 4;       // col 0..15
    const int kl = threadIdx.x & 15;
    const int colL = col0 + c;
    const int j = j0 + c;
#pragma unroll
    for (int kk = 0; kk < 4; ++kk) {
      const int k = k0 + kk * 64 + kl * 4;
      float4 wv; float s;
      if (k < 512) {
        wv = reinterpret_cast<const float4*>(w_ih)[(colL * 512 + k) >> 2];
        s = s_ih;
      } else {
        wv = reinterpret_cast<const float4*>(w_hh)[(colL * 512 + k - 512) >> 2];
        s = s_hh;
      }
      const int kt = k - k0;
      float xs[4] = {wv.x + nT[kt + 0][c] * s, wv.y + nT[kt + 1][c] * s,
                     wv.z + nT[kt + 2][c] * s, wv.w + nT[kt + 3][c] * s};
      ushort4 hi, lo;
      u16 h0 = f2bf(xs[0]); u16 l0 = f2bf(xs[0] - bf2f(h0));
      u16 h1 = f2bf(xs[1]); u16 l1 = f2bf(xs[1] - bf2f(h1));
      u16 h2 = f2bf(xs[2]); u16 l2 = f2bf(xs[2] - bf2f(h2));
      u16 h3 = f2bf(xs[3]); u16 l3 = f2bf(xs[3] - bf2f(h3));
      hi.x = h0; hi.y = h1; hi.z = h2; hi.w = h3;
      lo.x = l0; lo.y = l1; lo.z = l2; lo.w = l3;
      reinterpret_cast<ushort4*>(Whi)[(j * KD + k) >> 2] = hi;
      reinterpret_cast<ushort4*>(Wlo)[(j * KD + k) >> 2] = lo;
    }
  } else if (bid < 520) {
    int j = (bid - 512) * 256 + threadIdx.x;
    if (j < ND) {
      int g  = ((j >> 7) & 1) * 2 + ((j >> 4) & 1);
      int hb = ((j >> 8) << 2) | ((j >> 5) & 3);
      int col = g * 512 + (hb << 4) + (j & 15);
      biasC[j] = b_ih[col] + nb_ih[col] * (maxes[2] * 0.1f)
               + b_hh[col] + nb_hh[col] * (maxes[3] * 0.1f);
    }
  } else {
    const int total4 = NB * KD / 4;
    for (int e4 = (bid - 520) * 256 + threadIdx.x; e4 < total4;
         e4 += 2048 * 256) {
      int row = e4 >> 8;
      int c4  = e4 & 255;
      float4 v = (c4 < 128)
          ? reinterpret_cast<const float4*>(input)[row * 128 + c4]
          : reinterpret_cast<const float4*>(hx)[row * 128 + (c4 - 128)];
      float xs[4] = {v.x, v.y, v.z, v.w};
      ushort4 hi, lo;
      u16 h0 = f2bf(xs[0]); u16 l0 = f2bf(xs[0] - bf2f(h0));
      u16 h1 = f2bf(xs[1]); u16 l1 = f2bf(xs[1] - bf2f(h1));
      u16 h2 = f2bf(xs[2]); u16 l2 = f2bf(xs[2] - bf2f(h2));
      u16 h3 = f2bf(xs[3]); u16 l3 = f2bf(xs[3] - bf2f(h3));
      hi.x = h0; hi.y = h1; hi.z = h2; hi.w = h3;
      lo.x = l0; lo.y = l1; lo.z = l2; lo.w = l3;
      reinterpret_cast<ushort4*>(Xhi)[e4] = hi;
      reinterpret_cast<ushort4*>(Xlo)[e4] = lo;
    }
  }
}

// ---------- GEMM 256x256-tile, BK=32 unified (r3/r14 schedule; no setprio;
// B-resident XCD map: bn = blk&7 -> each XCD's 1 MB W panel stays L2-hot) ----------
// grid 256; 512 threads (8 waves, 2x4); LDS 128 KiB = 2 slots x 4 bufs x 16 KB.
// Per K=32 tile: 4 phases x 24 MFMA (3 terms: hihi + lohi + hilo).
__global__ __launch_bounds__(512, 2) void k_gemm_lstm(
    const u16* __restrict__ Xhi, const u16* __restrict__ Xlo,
    const u16* __restrict__ Whi, const u16* __restrict__ Wlo,
    const float* __restrict__ biasC, const float* __restrict__ cx,
    float* __restrict__ out) {
  __shared__ u16 L[2][4][8192];   // [slot][Ahi,Alo,Bhi,Blo][128x64]
  const int tid  = threadIdx.x;
  const int lane = tid & 63, wid = tid >> 6;
  const int wr = wid >> 2, wc = wid & 3;       // 2 x 4 waves
  const int lr = lane & 15, lg = lane >> 4;
  // B-resident map: with round-robin blk->XCD dispatch, bn = blk&7 pins one
  // 1 MB W panel per XCD (fits 4 MB L2); bm = blk>>3 streams A via L3.
  const int bn = blockIdx.x & 7;       // 0..7
  const int bm = blockIdx.x >> 3;      // 0..31
  const int mbase = bm * 256, nbase = bn * 256;

  // staging consts: lane l -> ldsrow (l>>3), lds chunk l&7, src chunk (l&7)^(l>>3)
  const int l8 = lane >> 3, l7 = lane & 7;
  const int csrc  = l7 ^ l8;
  const int srow  = wid * 16 + 2 * l8 + (csrc >> 2);  // global row offset in panel
  const int skoff = (csrc & 3) * 8;                   // k offset (u16)
  const int sdst  = wid * 512;                        // + HALF*4096 (u16)

  // frag-read per-thread swizzled offset (u16): row pair + chunk XOR
  const int fro = (lr >> 1) * 64 + ((((lr & 1) << 2) | lg) ^ ((lr >> 1) & 7)) * 8;

  f32x4 acc[8][4] = {};     // [mh*4+m2][gate = 2*nh+n2]
  bf16x8 afr[4][2];         // [m2][hi/lo]
  bf16x8 bfr[2][2][2];      // [nh][n2][hi/lo]

#define STAGE(V, BUF, HALF)                                                   \
  {                                                                           \
    const u16* arr_ = (BUF) == 0 ? Xhi : (BUF) == 1 ? Xlo                     \
                      : (BUF) == 2 ? Whi : Wlo;                               \
    const int gb_ = ((BUF) < 2 ? mbase : nbase) + (HALF) * 128 + srow;        \
    gload_lds16(arr_ + (size_t)gb_ * KD + (V) * 32 + skoff,                   \
                &L[(V) & 1][(BUF)][(HALF) * 4096 + sdst]);                    \
  }

#define PH(MH, NH, LOADA, LOADB, STAGE_CODE, WAIT_CODE)                       \
  {                                                                           \
    if (LOADA) {                                                              \
      _Pragma("unroll") for (int m2 = 0; m2 < 4; ++m2) {                      \
        const int ab = ((MH) * 128 + wr * 64 + m2 * 16) * 32 + fro;           \
        afr[m2][0] = *reinterpret_cast<const bf16x8*>(&L[s][0][ab]);          \
        afr[m2][1] = *reinterpret_cast<const bf16x8*>(&L[s][1][ab]);          \
      }                                                                       \
    }                                                                         \
    if (LOADB) {                                                              \
      _Pragma("unroll") for (int n2 = 0; n2 < 2; ++n2) {                      \
        const int bb = ((NH) * 128 + wc * 32 + n2 * 16) * 32 + fro;           \
        bfr[(NH)][n2][0] = *reinterpret_cast<const bf16x8*>(&L[s][2][bb]);    \
        bfr[(NH)][n2][1] = *reinterpret_cast<const bf16x8*>(&L[s][3][bb]);    \
      }                                                                       \
    }                                                                         \
    STAGE_CODE;                                                               \
    WAIT_CODE;                                                                \
    __builtin_amdgcn_s_barrier();                                             \
    _Pragma("unroll") for (int t = 0; t < 3; ++t)                             \
      _Pragma("unroll") for (int m2 = 0; m2 < 4; ++m2)                        \
        _Pragma("unroll") for (int n2 = 0; n2 < 2; ++n2) {                    \
          f32x4* ac = &acc[(MH) * 4 + m2][(NH) * 2 + n2];                     \
          *ac = __builtin_amdgcn_mfma_f32_16x16x32_bf16(afr[m2][t == 1],      \
                    bfr[(NH)][n2][t == 2], *ac, 0, 0, 0);                     \
        }                                                                     \
    __builtin_amdgcn_s_barrier();                                             \
  }

  // prologue: stage tile 0 in consumption order P1..P8
  STAGE(0, 0, 0); STAGE(0, 1, 0);   // Ahi.h0, Alo.h0
  STAGE(0, 2, 0); STAGE(0, 3, 0);   // Bhi.h0, Blo.h0
  STAGE(0, 2, 1); STAGE(0, 3, 1);   // Bhi.h1, Blo.h1
  STAGE(0, 0, 1); STAGE(0, 1, 1);   // Ahi.h1, Alo.h1
  asm volatile("s_waitcnt vmcnt(4)" ::: "memory");   // P1..P4 landed
  __builtin_amdgcn_s_barrier();

  int s = 0;
  for (int u = 0; u < NT - 1; ++u, s ^= 1) {
    // ph0 (mh0,nh0): reads P1..P4 data; stage N1,N2; wait -> P5,P6 for ph1
    PH(0, 0, 1, 1, { STAGE(u + 1, 0, 0); STAGE(u + 1, 1, 0); },
       asm volatile("s_waitcnt vmcnt(4)" ::: "memory"));
    // ph1 (mh0,nh1): reads P5,P6; stage N3,N4; wait -> P7,P8 for ph2
    PH(0, 1, 0, 1, { STAGE(u + 1, 2, 0); STAGE(u + 1, 3, 0); },
       asm volatile("s_waitcnt vmcnt(4)" ::: "memory"));
    // ph2 (mh1,nh1): reads P7,P8; stage N5,N6; no wait
    PH(1, 1, 1, 0, { STAGE(u + 1, 2, 1); STAGE(u + 1, 3, 1); }, );
    // ph3 (mh1,nh0): no reads; stage N7,N8; wait -> N1..N4 for next ph0
    PH(1, 0, 0, 0, { STAGE(u + 1, 0, 1); STAGE(u + 1, 1, 1); },
       asm volatile("s_waitcnt vmcnt(4)" ::: "memory"));
  }
  // peeled tile NT-1 (s == 1): no staging; drain
  PH(0, 0, 1, 1, , asm volatile("s_waitcnt vmcnt(2)" ::: "memory"));
  PH(0, 1, 0, 1, , asm volatile("s_waitcnt vmcnt(0)" ::: "memory"));
  PH(1, 1, 1, 0, , );
  PH(1, 0, 0, 0, , );

#undef PH
#undef STAGE

  // ---------- fused quantized-LSTM epilogue ----------
  const int hb = bn * 4 + wc;
  const int h = hb * 16 + lr;
  float bias[4];
#pragma unroll
  for (int g = 0; g < 4; ++g)
    bias[g] = biasC[bn * 256 + ((g >> 1) * 8 + wc * 2 + (g & 1)) * 16 + lr];
#pragma unroll
  for (int mh = 0; mh < 2; ++mh) {
#pragma unroll
    for (int m2 = 0; m2 < 4; ++m2) {
      const int m = mh * 4 + m2;
#pragma unroll
      for (int r = 0; r < 4; ++r) {
        const int row = mbase + mh * 128 + wr * 64 + m2 * 16 + lg * 4 + r;
        const float gi = acc[m][0][r] + bias[0];
        const float gf = acc[m][1][r] + bias[1];
        const float gc = acc[m][2][r] + bias[2];
        const float go = acc[m][3][r] + bias[3];
        const float ig = fq_u(sigm(gi));
        const float fg = fq_u(sigm(gf));
        const float cg = fq_s(tanhf(gc));
        const float og = fq_u(sigm(go));
        const float cxv = cx[(size_t)row * HD + h];
        const float t1 = fq_s(fg * cxv);
        const float t2 = fq_s(ig * cg);
        const float cyv = fq_s((t1 + t2) * 0.5f);
        const float hyv = fq_s(og * fq_s(tanhf(cyv * 2.0f)));
        out[(size_t)row * HD + h] = hyv;
        out[HY_OFF + (size_t)row * HD + h] = cyv;
      }
    }
  }
}

// ---------- launch ----------
extern "C" void kernel_launch(void* const* d_in, const int* in_sizes, int n_in,
                              void* d_out, int out_size, void* d_ws, size_t ws_size,
                              hipStream_t stream) {
  const float* input = (const float*)d_in[0];
  const float* hx    = (const float*)d_in[1];
  const float* cx    = (const float*)d_in[2];
  const float* w_ih  = (const float*)d_in[3];
  const float* w_hh  = (const float*)d_in[4];
  const float* b_ih  = (const float*)d_in[5];
  const float* b_hh  = (const float*)d_in[6];
  const float* n_ih  = (const float*)d_in[7];
  const float* n_hh  = (const float*)d_in[8];
  const float* nb_ih = (const float*)d_in[9];
  const float* nb_hh = (const float*)d_in[10];
  float* out = (float*)d_out;

  char* ws = (char*)d_ws;
  float* maxes = (float*)ws;                                   // 16 B (+pad to 256)
  u16* Xhi = (u16*)(ws + 256);                                 // 16 MB
  u16* Xlo = (u16*)(ws + 256 + 16777216);                      // 16 MB
  u16* Whi = (u16*)(ws + 256 + 2 * 16777216);                  // 4 MB
  u16* Wlo = (u16*)(ws + 256 + 2 * 16777216 + 4194304);        // 4 MB
  float* biasC = (float*)(ws + 256 + 2 * 16777216 + 2 * 4194304); // 8 KB

  hipMemsetAsync(maxes, 0xFF, 16, stream);  // -NaN sentinel; atomic lattice fixes it
  hipLaunchKernelGGL(k_max, dim3(514), dim3(256), 0, stream,
                     w_ih, w_hh, b_ih, b_hh, maxes);
  hipLaunchKernelGGL(k_prep, dim3(2568), dim3(256), 0, stream,
                     input, hx, w_ih, w_hh, n_ih, n_hh, b_ih, b_hh,
                     nb_ih, nb_hh, maxes, Xhi, Xlo, Whi, Wlo, biasC);
  hipLaunchKernelGGL(k_gemm_lstm, dim3(256), dim3(512), 0, stream,
                     Xhi, Xlo, Whi, Wlo, biasC, cx, out);
}

// Round 16
// 123.868 us; speedup vs baseline: 1.2249x; 1.0000x over previous
//
#include <hip/hip_runtime.h>
#include <cstdint>

typedef unsigned short u16;
typedef __bf16 bf16x8 __attribute__((ext_vector_type(8)));
typedef float f32x4 __attribute__((ext_vector_type(4)));

#define NB 8192          // batch rows
#define HD 512           // hidden
#define KD 1024          // IN + H
#define ND 2048          // 4H (physical, column-reordered)
#define HY_OFF (NB * HD) // offset of cy in d_out
#define NT 32            // K-tiles of BK=32

// ---------- helpers ----------
__device__ __forceinline__ u16 f2bf(float f) {
  unsigned u = __float_as_uint(f);
  u += 0x7FFFu + ((u >> 16) & 1u);          // round-to-nearest-even bf16
  return (u16)(u >> 16);
}
__device__ __forceinline__ float bf2f(u16 h) {
  return __uint_as_float(((unsigned)h) << 16);
}
__device__ __forceinline__ void atomicMaxF(float* a, float v) {
  if (v >= 0.f) atomicMax((int*)a, __float_as_int(v));
  else          atomicMin((unsigned int*)a, __float_as_uint(v));
}
__device__ __forceinline__ float fq_u(float x) {           // unsigned 8-bit fake-quant
  float xc = fminf(fmaxf(x, 0.0f), 1.0f);
  return rintf(xc * 256.0f) * (1.0f / 256.0f);
}
__device__ __forceinline__ float fq_s(float x) {           // signed 8-bit fake-quant
  const float lim = 1.0f - 1.0f / 128.0f;
  float xc = fminf(fmaxf(x, -lim), lim);
  return rintf(xc * 128.0f) * (1.0f / 128.0f);
}
__device__ __forceinline__ float sigm(float x) { return 1.0f / (1.0f + expf(-x)); }

__device__ __forceinline__ void gload_lds16(const u16* g, u16* l) {
  __builtin_amdgcn_global_load_lds(
      (const __attribute__((address_space(1))) void*)g,
      (__attribute__((address_space(3))) void*)l, 16, 0, 0);
}

// ---------- k_max: minimal max-reduce (float4) ----------
// blocks [0,256): w_ih ; [256,512): w_hh ; 512: b_ih ; 513: b_hh
__global__ __launch_bounds__(256) void k_max(
    const float* __restrict__ w_ih, const float* __restrict__ w_hh,
    const float* __restrict__ b_ih, const float* __restrict__ b_hh,
    float* __restrict__ maxes) {
  const int bid = blockIdx.x;
  const float4* src; int slot, base4, n4;
  if (bid < 256)      { src = (const float4*)w_ih; slot = 0; base4 = bid * 1024; n4 = 1024; }
  else if (bid < 512) { src = (const float4*)w_hh; slot = 1; base4 = (bid - 256) * 1024; n4 = 1024; }
  else if (bid == 512){ src = (const float4*)b_ih; slot = 2; base4 = 0; n4 = 512; }
  else                { src = (const float4*)b_hh; slot = 3; base4 = 0; n4 = 512; }
  float m = -INFINITY;
  for (int i = threadIdx.x; i < n4; i += 256) {
    float4 v = src[base4 + i];
    m = fmaxf(m, fmaxf(fmaxf(v.x, v.y), fmaxf(v.z, v.w)));
  }
  for (int k = 1; k < 64; k <<= 1) m = fmaxf(m, __shfl_xor(m, k, 64));
  __shared__ float sm[4];
  if ((threadIdx.x & 63) == 0) sm[threadIdx.x >> 6] = m;
  __syncthreads();
  if (threadIdx.x == 0) {
    m = fmaxf(fmaxf(sm[0], sm[1]), fmaxf(sm[2], sm[3]));
    atomicMaxF(&maxes[slot], m);
  }
}

// ---------- fused prep: split X FIRST (streaming saturates HBM), then W, bias ----------
// blocks [0,2048): split X ; [2048,2560): W (16 cols x 256 k each) ; [2560,2568): bias
// W physical j bits: [10:8]=bn, [7]=nh, [6:5]=wc, [4]=n2, [3:0]=lane
// gate g = 2*nh + n2 ; h-block hb = bn*4 + wc ; logical col = g*512 + hb*16 + j[3:0]
__global__ __launch_bounds__(256) void k_prep(
    const float* __restrict__ input, const float* __restrict__ hx,
    const float* __restrict__ w_ih, const float* __restrict__ w_hh,
    const float* __restrict__ n_ih, const float* __restrict__ n_hh,
    const float* __restrict__ b_ih, const float* __restrict__ b_hh,
    const float* __restrict__ nb_ih, const float* __restrict__ nb_hh,
    const float* __restrict__ maxes,
    u16* __restrict__ Xhi, u16* __restrict__ Xlo,
    u16* __restrict__ Whi, u16* __restrict__ Wlo,
    float* __restrict__ biasC) {
  const int bid = blockIdx.x;
  if (bid < 2048) {
    const int total4 = NB * KD / 4;
    for (int e4 = bid * 256 + threadIdx.x; e4 < total4; e4 += 2048 * 256) {
      int row = e4 >> 8;
      int c4  = e4 & 255;
      float4 v = (c4 < 128)
          ? reinterpret_cast<const float4*>(input)[row * 128 + c4]
          : reinterpret_cast<const float4*>(hx)[row * 128 + (c4 - 128)];
      float xs[4] = {v.x, v.y, v.z, v.w};
      ushort4 hi, lo;
      u16 h0 = f2bf(xs[0]); u16 l0 = f2bf(xs[0] - bf2f(h0));
      u16 h1 = f2bf(xs[1]); u16 l1 = f2bf(xs[1] - bf2f(h1));
      u16 h2 = f2bf(xs[2]); u16 l2 = f2bf(xs[2] - bf2f(h2));
      u16 h3 = f2bf(xs[3]); u16 l3 = f2bf(xs[3] - bf2f(h3));
      hi.x = h0; hi.y = h1; hi.z = h2; hi.w = h3;
      lo.x = l0; lo.y = l1; lo.z = l2; lo.w = l3;
      reinterpret_cast<ushort4*>(Xhi)[e4] = hi;
      reinterpret_cast<ushort4*>(Xlo)[e4] = lo;
    }
  } else if (bid < 2560) {
    // one block: 16 physical cols (one lane-group) x 256 k-rows
    __shared__ float nT[256][17];   // padded transpose buffer (17 KB)
    const int w  = bid - 2048;      // 0..511
    const int cg = w >> 2, kb = w & 3;
    const int j0 = cg * 16;
    const int g  = ((j0 >> 7) & 1) * 2 + ((j0 >> 4) & 1);
    const int hb = ((j0 >> 8) << 2) | ((j0 >> 5) & 3);
    const int col0 = g * 512 + (hb << 4);
    const int k0 = kb * 256;
    {  // stage noise[k0..k0+256)[col0..col0+16) -> nT, coalesced
      const int cl = threadIdx.x & 15;
      const int kr = threadIdx.x >> 4;
#pragma unroll 4
      for (int i = 0; i < 16; ++i) {
        const int k = k0 + kr + 16 * i;
        nT[kr + 16 * i][cl] = (k < 512) ? n_ih[k * ND + col0 + cl]
                                        : n_hh[(k - 512) * ND + col0 + cl];
      }
    }
    __syncthreads();
    const float s_ih = maxes[0] * 0.1f, s_hh = maxes[1] * 0.1f;
    const int c  = threadIdx.x >> 4;       // col 0..15
    const int kl = threadIdx.x & 15;
    const int colL = col0 + c;
    const int j = j0 + c;
#pragma unroll
    for (int kk = 0; kk < 4; ++kk) {
      const int k = k0 + kk * 64 + kl * 4;
      float4 wv; float s;
      if (k < 512) {
        wv = reinterpret_cast<const float4*>(w_ih)[(colL * 512 + k) >> 2];
        s = s_ih;
      } else {
        wv = reinterpret_cast<const float4*>(w_hh)[(colL * 512 + k - 512) >> 2];
        s = s_hh;
      }
      const int kt = k - k0;
      float xs[4] = {wv.x + nT[kt + 0][c] * s, wv.y + nT[kt + 1][c] * s,
                     wv.z + nT[kt + 2][c] * s, wv.w + nT[kt + 3][c] * s};
      ushort4 hi, lo;
      u16 h0 = f2bf(xs[0]); u16 l0 = f2bf(xs[0] - bf2f(h0));
      u16 h1 = f2bf(xs[1]); u16 l1 = f2bf(xs[1] - bf2f(h1));
      u16 h2 = f2bf(xs[2]); u16 l2 = f2bf(xs[2] - bf2f(h2));
      u16 h3 = f2bf(xs[3]); u16 l3 = f2bf(xs[3] - bf2f(h3));
      hi.x = h0; hi.y = h1; hi.z = h2; hi.w = h3;
      lo.x = l0; lo.y = l1; lo.z = l2; lo.w = l3;
      reinterpret_cast<ushort4*>(Whi)[(j * KD + k) >> 2] = hi;
      reinterpret_cast<ushort4*>(Wlo)[(j * KD + k) >> 2] = lo;
    }
  } else {
    int j = (bid - 2560) * 256 + threadIdx.x;
    if (j < ND) {
      int g  = ((j >> 7) & 1) * 2 + ((j >> 4) & 1);
      int hb = ((j >> 8) << 2) | ((j >> 5) & 3);
      int col = g * 512 + (hb << 4) + (j & 15);
      biasC[j] = b_ih[col] + nb_ih[col] * (maxes[2] * 0.1f)
               + b_hh[col] + nb_hh[col] * (maxes[3] * 0.1f);
    }
  }
}

// ---------- GEMM 256x256-tile, BK=32 unified (r15 verbatim: no setprio,
// B-resident XCD map: bn = blk&7 -> each XCD's 1 MB W panel stays L2-hot) ----------
// grid 256; 512 threads (8 waves, 2x4); LDS 128 KiB = 2 slots x 4 bufs x 16 KB.
// Per K=32 tile: 4 phases x 24 MFMA (3 terms: hihi + lohi + hilo).
__global__ __launch_bounds__(512, 2) void k_gemm_lstm(
    const u16* __restrict__ Xhi, const u16* __restrict__ Xlo,
    const u16* __restrict__ Whi, const u16* __restrict__ Wlo,
    const float* __restrict__ biasC, const float* __restrict__ cx,
    float* __restrict__ out) {
  __shared__ u16 L[2][4][8192];   // [slot][Ahi,Alo,Bhi,Blo][128x64]
  const int tid  = threadIdx.x;
  const int lane = tid & 63, wid = tid >> 6;
  const int wr = wid >> 2, wc = wid & 3;       // 2 x 4 waves
  const int lr = lane & 15, lg = lane >> 4;
  // B-resident map: with round-robin blk->XCD dispatch, bn = blk&7 pins one
  // 1 MB W panel per XCD (fits 4 MB L2); bm = blk>>3 streams A via L3.
  const int bn = blockIdx.x & 7;       // 0..7
  const int bm = blockIdx.x >> 3;      // 0..31
  const int mbase = bm * 256, nbase = bn * 256;

  // staging consts: lane l -> ldsrow (l>>3), lds chunk l&7, src chunk (l&7)^(l>>3)
  const int l8 = lane >> 3, l7 = lane & 7;
  const int csrc  = l7 ^ l8;
  const int srow  = wid * 16 + 2 * l8 + (csrc >> 2);  // global row offset in panel
  const int skoff = (csrc & 3) * 8;                   // k offset (u16)
  const int sdst  = wid * 512;                        // + HALF*4096 (u16)

  // frag-read per-thread swizzled offset (u16): row pair + chunk XOR
  const int fro = (lr >> 1) * 64 + ((((lr & 1) << 2) | lg) ^ ((lr >> 1) & 7)) * 8;

  f32x4 acc[8][4] = {};     // [mh*4+m2][gate = 2*nh+n2]
  bf16x8 afr[4][2];         // [m2][hi/lo]
  bf16x8 bfr[2][2][2];      // [nh][n2][hi/lo]

#define STAGE(V, BUF, HALF)                                                   \
  {                                                                           \
    const u16* arr_ = (BUF) == 0 ? Xhi : (BUF) == 1 ? Xlo                     \
                      : (BUF) == 2 ? Whi : Wlo;                               \
    const int gb_ = ((BUF) < 2 ? mbase : nbase) + (HALF) * 128 + srow;        \
    gload_lds16(arr_ + (size_t)gb_ * KD + (V) * 32 + skoff,                   \
                &L[(V) & 1][(BUF)][(HALF) * 4096 + sdst]);                    \
  }

#define PH(MH, NH, LOADA, LOADB, STAGE_CODE, WAIT_CODE)                       \
  {                                                                           \
    if (LOADA) {                                                              \
      _Pragma("unroll") for (int m2 = 0; m2 < 4; ++m2) {                      \
        const int ab = ((MH) * 128 + wr * 64 + m2 * 16) * 32 + fro;           \
        afr[m2][0] = *reinterpret_cast<const bf16x8*>(&L[s][0][ab]);          \
        afr[m2][1] = *reinterpret_cast<const bf16x8*>(&L[s][1][ab]);          \
      }                                                                       \
    }                                                                         \
    if (LOADB) {                                                              \
      _Pragma("unroll") for (int n2 = 0; n2 < 2; ++n2) {                      \
        const int bb = ((NH) * 128 + wc * 32 + n2 * 16) * 32 + fro;           \
        bfr[(NH)][n2][0] = *reinterpret_cast<const bf16x8*>(&L[s][2][bb]);    \
        bfr[(NH)][n2][1] = *reinterpret_cast<const bf16x8*>(&L[s][3][bb]);    \
      }                                                                       \
    }                                                                         \
    STAGE_CODE;                                                               \
    WAIT_CODE;                                                                \
    __builtin_amdgcn_s_barrier();                                             \
    _Pragma("unroll") for (int t = 0; t < 3; ++t)                             \
      _Pragma("unroll") for (int m2 = 0; m2 < 4; ++m2)                        \
        _Pragma("unroll") for (int n2 = 0; n2 < 2; ++n2) {                    \
          f32x4* ac = &acc[(MH) * 4 + m2][(NH) * 2 + n2];                     \
          *ac = __builtin_amdgcn_mfma_f32_16x16x32_bf16(afr[m2][t == 1],      \
                    bfr[(NH)][n2][t == 2], *ac, 0, 0, 0);                     \
        }                                                                     \
    __builtin_amdgcn_s_barrier();                                             \
  }

  // prologue: stage tile 0 in consumption order P1..P8
  STAGE(0, 0, 0); STAGE(0, 1, 0);   // Ahi.h0, Alo.h0
  STAGE(0, 2, 0); STAGE(0, 3, 0);   // Bhi.h0, Blo.h0
  STAGE(0, 2, 1); STAGE(0, 3, 1);   // Bhi.h1, Blo.h1
  STAGE(0, 0, 1); STAGE(0, 1, 1);   // Ahi.h1, Alo.h1
  asm volatile("s_waitcnt vmcnt(4)" ::: "memory");   // P1..P4 landed
  __builtin_amdgcn_s_barrier();

  int s = 0;
  for (int u = 0; u < NT - 1; ++u, s ^= 1) {
    // ph0 (mh0,nh0): reads P1..P4 data; stage N1,N2; wait -> P5,P6 for ph1
    PH(0, 0, 1, 1, { STAGE(u + 1, 0, 0); STAGE(u + 1, 1, 0); },
       asm volatile("s_waitcnt vmcnt(4)" ::: "memory"));
    // ph1 (mh0,nh1): reads P5,P6; stage N3,N4; wait -> P7,P8 for ph2
    PH(0, 1, 0, 1, { STAGE(u + 1, 2, 0); STAGE(u + 1, 3, 0); },
       asm volatile("s_waitcnt vmcnt(4)" ::: "memory"));
    // ph2 (mh1,nh1): reads P7,P8; stage N5,N6; no wait
    PH(1, 1, 1, 0, { STAGE(u + 1, 2, 1); STAGE(u + 1, 3, 1); }, );
    // ph3 (mh1,nh0): no reads; stage N7,N8; wait -> N1..N4 for next ph0
    PH(1, 0, 0, 0, { STAGE(u + 1, 0, 1); STAGE(u + 1, 1, 1); },
       asm volatile("s_waitcnt vmcnt(4)" ::: "memory"));
  }
  // peeled tile NT-1 (s == 1): no staging; drain
  PH(0, 0, 1, 1, , asm volatile("s_waitcnt vmcnt(2)" ::: "memory"));
  PH(0, 1, 0, 1, , asm volatile("s_waitcnt vmcnt(0)" ::: "memory"));
  PH(1, 1, 1, 0, , );
  PH(1, 0, 0, 0, , );

#undef PH
#undef STAGE

  // ---------- fused quantized-LSTM epilogue ----------
  const int hb = bn * 4 + wc;
  const int h = hb * 16 + lr;
  float bias[4];
#pragma unroll
  for (int g = 0; g < 4; ++g)
    bias[g] = biasC[bn * 256 + ((g >> 1) * 8 + wc * 2 + (g & 1)) * 16 + lr];
#pragma unroll
  for (int mh = 0; mh < 2; ++mh) {
#pragma unroll
    for (int m2 = 0; m2 < 4; ++m2) {
      const int m = mh * 4 + m2;
#pragma unroll
      for (int r = 0; r < 4; ++r) {
        const int row = mbase + mh * 128 + wr * 64 + m2 * 16 + lg * 4 + r;
        const float gi = acc[m][0][r] + bias[0];
        const float gf = acc[m][1][r] + bias[1];
        const float gc = acc[m][2][r] + bias[2];
        const float go = acc[m][3][r] + bias[3];
        const float ig = fq_u(sigm(gi));
        const float fg = fq_u(sigm(gf));
        const float cg = fq_s(tanhf(gc));
        const float og = fq_u(sigm(go));
        const float cxv = cx[(size_t)row * HD + h];
        const float t1 = fq_s(fg * cxv);
        const float t2 = fq_s(ig * cg);
        const float cyv = fq_s((t1 + t2) * 0.5f);
        const float hyv = fq_s(og * fq_s(tanhf(cyv * 2.0f)));
        out[(size_t)row * HD + h] = hyv;
        out[HY_OFF + (size_t)row * HD + h] = cyv;
      }
    }
  }
}

// ---------- launch ----------
extern "C" void kernel_launch(void* const* d_in, const int* in_sizes, int n_in,
                              void* d_out, int out_size, void* d_ws, size_t ws_size,
                              hipStream_t stream) {
  const float* input = (const float*)d_in[0];
  const float* hx    = (const float*)d_in[1];
  const float* cx    = (const float*)d_in[2];
  const float* w_ih  = (const float*)d_in[3];
  const float* w_hh  = (const float*)d_in[4];
  const float* b_ih  = (const float*)d_in[5];
  const float* b_hh  = (const float*)d_in[6];
  const float* n_ih  = (const float*)d_in[7];
  const float* n_hh  = (const float*)d_in[8];
  const float* nb_ih = (const float*)d_in[9];
  const float* nb_hh = (const float*)d_in[10];
  float* out = (float*)d_out;

  char* ws = (char*)d_ws;
  float* maxes = (float*)ws;                                   // 16 B (+pad to 256)
  u16* Xhi = (u16*)(ws + 256);                                 // 16 MB
  u16* Xlo = (u16*)(ws + 256 + 16777216);                      // 16 MB
  u16* Whi = (u16*)(ws + 256 + 2 * 16777216);                  // 4 MB
  u16* Wlo = (u16*)(ws + 256 + 2 * 16777216 + 4194304);        // 4 MB
  float* biasC = (float*)(ws + 256 + 2 * 16777216 + 2 * 4194304); // 8 KB

  hipMemsetAsync(maxes, 0xFF, 16, stream);  // -NaN sentinel; atomic lattice fixes it
  hipLaunchKernelGGL(k_max, dim3(514), dim3(256), 0, stream,
                     w_ih, w_hh, b_ih, b_hh, maxes);
  hipLaunchKernelGGL(k_prep, dim3(2568), dim3(256), 0, stream,
                     input, hx, w_ih, w_hh, n_ih, n_hh, b_ih, b_hh,
                     nb_ih, nb_hh, maxes, Xhi, Xlo, Whi, Wlo, biasC);
  hipLaunchKernelGGL(k_gemm_lstm, dim3(256), dim3(512), 0, stream,
                     Xhi, Xlo, Whi, Wlo, biasC, cx, out);
}

// Round 17
// 123.112 us; speedup vs baseline: 1.2324x; 1.0061x over previous
//
#include <hip/hip_runtime.h>
#include <cstdint>

typedef unsigned short u16;
typedef __bf16 bf16x8 __attribute__((ext_vector_type(8)));
typedef float f32x4 __attribute__((ext_vector_type(4)));

#define NB 8192          // batch rows
#define HD 512           // hidden
#define KD 1024          // IN + H
#define ND 2048          // 4H (physical, column-reordered)
#define HY_OFF (NB * HD) // offset of cy in d_out
#define NT 32            // K-tiles of BK=32

// ---------- helpers ----------
__device__ __forceinline__ u16 f2bf(float f) {
  unsigned u = __float_as_uint(f);
  u += 0x7FFFu + ((u >> 16) & 1u);          // round-to-nearest-even bf16
  return (u16)(u >> 16);
}
__device__ __forceinline__ float bf2f(u16 h) {
  return __uint_as_float(((unsigned)h) << 16);
}
__device__ __forceinline__ void atomicMaxF(float* a, float v) {
  if (v >= 0.f) atomicMax((int*)a, __float_as_int(v));
  else          atomicMin((unsigned int*)a, __float_as_uint(v));
}
__device__ __forceinline__ float fq_u(float x) {           // unsigned 8-bit fake-quant
  float xc = fminf(fmaxf(x, 0.0f), 1.0f);
  return rintf(xc * 256.0f) * (1.0f / 256.0f);
}
__device__ __forceinline__ float fq_s(float x) {           // signed 8-bit fake-quant
  const float lim = 1.0f - 1.0f / 128.0f;
  float xc = fminf(fmaxf(x, -lim), lim);
  return rintf(xc * 128.0f) * (1.0f / 128.0f);
}
__device__ __forceinline__ float sigm(float x) { return 1.0f / (1.0f + expf(-x)); }

__device__ __forceinline__ void gload_lds16(const u16* g, u16* l) {
  __builtin_amdgcn_global_load_lds(
      (const __attribute__((address_space(1))) void*)g,
      (__attribute__((address_space(3))) void*)l, 16, 0, 0);
}

// ---------- k_max: minimal max-reduce (float4) ----------
// blocks [0,256): w_ih ; [256,512): w_hh ; 512: b_ih ; 513: b_hh
__global__ __launch_bounds__(256) void k_max(
    const float* __restrict__ w_ih, const float* __restrict__ w_hh,
    const float* __restrict__ b_ih, const float* __restrict__ b_hh,
    float* __restrict__ maxes) {
  const int bid = blockIdx.x;
  const float4* src; int slot, base4, n4;
  if (bid < 256)      { src = (const float4*)w_ih; slot = 0; base4 = bid * 1024; n4 = 1024; }
  else if (bid < 512) { src = (const float4*)w_hh; slot = 1; base4 = (bid - 256) * 1024; n4 = 1024; }
  else if (bid == 512){ src = (const float4*)b_ih; slot = 2; base4 = 0; n4 = 512; }
  else                { src = (const float4*)b_hh; slot = 3; base4 = 0; n4 = 512; }
  float m = -INFINITY;
  for (int i = threadIdx.x; i < n4; i += 256) {
    float4 v = src[base4 + i];
    m = fmaxf(m, fmaxf(fmaxf(v.x, v.y), fmaxf(v.z, v.w)));
  }
  for (int k = 1; k < 64; k <<= 1) m = fmaxf(m, __shfl_xor(m, k, 64));
  __shared__ float sm[4];
  if ((threadIdx.x & 63) == 0) sm[threadIdx.x >> 6] = m;
  __syncthreads();
  if (threadIdx.x == 0) {
    m = fmaxf(fmaxf(sm[0], sm[1]), fmaxf(sm[2], sm[3]));
    atomicMaxF(&maxes[slot], m);
  }
}

// ---------- fused prep: X-split and W-build INTERLEAVED 4:1, bias tail ----------
// blocks [0,2560): bid%5<4 -> X-split (xi = (bid/5)*4 + bid%5),
//                  bid%5==4 -> W-build (wi = bid/5)  [W overlaps the X stream]
// blocks [2560,2568): bias
// W physical j bits: [10:8]=bn, [7]=nh, [6:5]=wc, [4]=n2, [3:0]=lane
// gate g = 2*nh + n2 ; h-block hb = bn*4 + wc ; logical col = g*512 + hb*16 + j[3:0]
__global__ __launch_bounds__(256) void k_prep(
    const float* __restrict__ input, const float* __restrict__ hx,
    const float* __restrict__ w_ih, const float* __restrict__ w_hh,
    const float* __restrict__ n_ih, const float* __restrict__ n_hh,
    const float* __restrict__ b_ih, const float* __restrict__ b_hh,
    const float* __restrict__ nb_ih, const float* __restrict__ nb_hh,
    const float* __restrict__ maxes,
    u16* __restrict__ Xhi, u16* __restrict__ Xlo,
    u16* __restrict__ Whi, u16* __restrict__ Wlo,
    float* __restrict__ biasC) {
  const int bid = blockIdx.x;
  if (bid < 2560 && (bid % 5) < 4) {
    const int xi = (bid / 5) * 4 + (bid % 5);
    const int total4 = NB * KD / 4;
    for (int e4 = xi * 256 + threadIdx.x; e4 < total4; e4 += 2048 * 256) {
      int row = e4 >> 8;
      int c4  = e4 & 255;
      float4 v = (c4 < 128)
          ? reinterpret_cast<const float4*>(input)[row * 128 + c4]
          : reinterpret_cast<const float4*>(hx)[row * 128 + (c4 - 128)];
      float xs[4] = {v.x, v.y, v.z, v.w};
      ushort4 hi, lo;
      u16 h0 = f2bf(xs[0]); u16 l0 = f2bf(xs[0] - bf2f(h0));
      u16 h1 = f2bf(xs[1]); u16 l1 = f2bf(xs[1] - bf2f(h1));
      u16 h2 = f2bf(xs[2]); u16 l2 = f2bf(xs[2] - bf2f(h2));
      u16 h3 = f2bf(xs[3]); u16 l3 = f2bf(xs[3] - bf2f(h3));
      hi.x = h0; hi.y = h1; hi.z = h2; hi.w = h3;
      lo.x = l0; lo.y = l1; lo.z = l2; lo.w = l3;
      reinterpret_cast<ushort4*>(Xhi)[e4] = hi;
      reinterpret_cast<ushort4*>(Xlo)[e4] = lo;
    }
  } else if (bid < 2560) {
    // one block: 16 physical cols (one lane-group) x 256 k-rows
    __shared__ float nT[256][17];   // padded transpose buffer (17 KB)
    const int w  = bid / 5;         // 0..511
    const int cg = w >> 2, kb = w & 3;
    const int j0 = cg * 16;
    const int g  = ((j0 >> 7) & 1) * 2 + ((j0 >> 4) & 1);
    const int hb = ((j0 >> 8) << 2) | ((j0 >> 5) & 3);
    const int col0 = g * 512 + (hb << 4);
    const int k0 = kb * 256;
    {  // stage noise[k0..k0+256)[col0..col0+16) -> nT, coalesced
      const int cl = threadIdx.x & 15;
      const int kr = threadIdx.x >> 4;
#pragma unroll 4
      for (int i = 0; i < 16; ++i) {
        const int k = k0 + kr + 16 * i;
        nT[kr + 16 * i][cl] = (k < 512) ? n_ih[k * ND + col0 + cl]
                                        : n_hh[(k - 512) * ND + col0 + cl];
      }
    }
    __syncthreads();
    const float s_ih = maxes[0] * 0.1f, s_hh = maxes[1] * 0.1f;
    const int c  = threadIdx.x >> 4;       // col 0..15
    const int kl = threadIdx.x & 15;
    const int colL = col0 + c;
    const int j = j0 + c;
#pragma unroll
    for (int kk = 0; kk < 4; ++kk) {
      const int k = k0 + kk * 64 + kl * 4;
      float4 wv; float s;
      if (k < 512) {
        wv = reinterpret_cast<const float4*>(w_ih)[(colL * 512 + k) >> 2];
        s = s_ih;
      } else {
        wv = reinterpret_cast<const float4*>(w_hh)[(colL * 512 + k - 512) >> 2];
        s = s_hh;
      }
      const int kt = k - k0;
      float xs[4] = {wv.x + nT[kt + 0][c] * s, wv.y + nT[kt + 1][c] * s,
                     wv.z + nT[kt + 2][c] * s, wv.w + nT[kt + 3][c] * s};
      ushort4 hi, lo;
      u16 h0 = f2bf(xs[0]); u16 l0 = f2bf(xs[0] - bf2f(h0));
      u16 h1 = f2bf(xs[1]); u16 l1 = f2bf(xs[1] - bf2f(h1));
      u16 h2 = f2bf(xs[2]); u16 l2 = f2bf(xs[2] - bf2f(h2));
      u16 h3 = f2bf(xs[3]); u16 l3 = f2bf(xs[3] - bf2f(h3));
      hi.x = h0; hi.y = h1; hi.z = h2; hi.w = h3;
      lo.x = l0; lo.y = l1; lo.z = l2; lo.w = l3;
      reinterpret_cast<ushort4*>(Whi)[(j * KD + k) >> 2] = hi;
      reinterpret_cast<ushort4*>(Wlo)[(j * KD + k) >> 2] = lo;
    }
  } else {
    int j = (bid - 2560) * 256 + threadIdx.x;
    if (j < ND) {
      int g  = ((j >> 7) & 1) * 2 + ((j >> 4) & 1);
      int hb = ((j >> 8) << 2) | ((j >> 5) & 3);
      int col = g * 512 + (hb << 4) + (j & 15);
      biasC[j] = b_ih[col] + nb_ih[col] * (maxes[2] * 0.1f)
               + b_hh[col] + nb_hh[col] * (maxes[3] * 0.1f);
    }
  }
}

// ---------- GEMM 256x256-tile, BK=32 unified (r16 verbatim: no setprio,
// B-resident XCD map: bn = blk&7 -> each XCD's 1 MB W panel stays L2-hot) ----------
// grid 256; 512 threads (8 waves, 2x4); LDS 128 KiB = 2 slots x 4 bufs x 16 KB.
// Per K=32 tile: 4 phases x 24 MFMA (3 terms: hihi + lohi + hilo).
__global__ __launch_bounds__(512, 2) void k_gemm_lstm(
    const u16* __restrict__ Xhi, const u16* __restrict__ Xlo,
    const u16* __restrict__ Whi, const u16* __restrict__ Wlo,
    const float* __restrict__ biasC, const float* __restrict__ cx,
    float* __restrict__ out) {
  __shared__ u16 L[2][4][8192];   // [slot][Ahi,Alo,Bhi,Blo][128x64]
  const int tid  = threadIdx.x;
  const int lane = tid & 63, wid = tid >> 6;
  const int wr = wid >> 2, wc = wid & 3;       // 2 x 4 waves
  const int lr = lane & 15, lg = lane >> 4;
  // B-resident map: with round-robin blk->XCD dispatch, bn = blk&7 pins one
  // 1 MB W panel per XCD (fits 4 MB L2); bm = blk>>3 streams A via L3.
  const int bn = blockIdx.x & 7;       // 0..7
  const int bm = blockIdx.x >> 3;      // 0..31
  const int mbase = bm * 256, nbase = bn * 256;

  // staging consts: lane l -> ldsrow (l>>3), lds chunk l&7, src chunk (l&7)^(l>>3)
  const int l8 = lane >> 3, l7 = lane & 7;
  const int csrc  = l7 ^ l8;
  const int srow  = wid * 16 + 2 * l8 + (csrc >> 2);  // global row offset in panel
  const int skoff = (csrc & 3) * 8;                   // k offset (u16)
  const int sdst  = wid * 512;                        // + HALF*4096 (u16)

  // frag-read per-thread swizzled offset (u16): row pair + chunk XOR
  const int fro = (lr >> 1) * 64 + ((((lr & 1) << 2) | lg) ^ ((lr >> 1) & 7)) * 8;

  f32x4 acc[8][4] = {};     // [mh*4+m2][gate = 2*nh+n2]
  bf16x8 afr[4][2];         // [m2][hi/lo]
  bf16x8 bfr[2][2][2];      // [nh][n2][hi/lo]

#define STAGE(V, BUF, HALF)                                                   \
  {                                                                           \
    const u16* arr_ = (BUF) == 0 ? Xhi : (BUF) == 1 ? Xlo                     \
                      : (BUF) == 2 ? Whi : Wlo;                               \
    const int gb_ = ((BUF) < 2 ? mbase : nbase) + (HALF) * 128 + srow;        \
    gload_lds16(arr_ + (size_t)gb_ * KD + (V) * 32 + skoff,                   \
                &L[(V) & 1][(BUF)][(HALF) * 4096 + sdst]);                    \
  }

#define PH(MH, NH, LOADA, LOADB, STAGE_CODE, WAIT_CODE)                       \
  {                                                                           \
    if (LOADA) {                                                              \
      _Pragma("unroll") for (int m2 = 0; m2 < 4; ++m2) {                      \
        const int ab = ((MH) * 128 + wr * 64 + m2 * 16) * 32 + fro;           \
        afr[m2][0] = *reinterpret_cast<const bf16x8*>(&L[s][0][ab]);          \
        afr[m2][1] = *reinterpret_cast<const bf16x8*>(&L[s][1][ab]);          \
      }                                                                       \
    }                                                                         \
    if (LOADB) {                                                              \
      _Pragma("unroll") for (int n2 = 0; n2 < 2; ++n2) {                      \
        const int bb = ((NH) * 128 + wc * 32 + n2 * 16) * 32 + fro;           \
        bfr[(NH)][n2][0] = *reinterpret_cast<const bf16x8*>(&L[s][2][bb]);    \
        bfr[(NH)][n2][1] = *reinterpret_cast<const bf16x8*>(&L[s][3][bb]);    \
      }                                                                       \
    }                                                                         \
    STAGE_CODE;                                                               \
    WAIT_CODE;                                                                \
    __builtin_amdgcn_s_barrier();                                             \
    _Pragma("unroll") for (int t = 0; t < 3; ++t)                             \
      _Pragma("unroll") for (int m2 = 0; m2 < 4; ++m2)                        \
        _Pragma("unroll") for (int n2 = 0; n2 < 2; ++n2) {                    \
          f32x4* ac = &acc[(MH) * 4 + m2][(NH) * 2 + n2];                     \
          *ac = __builtin_amdgcn_mfma_f32_16x16x32_bf16(afr[m2][t == 1],      \
                    bfr[(NH)][n2][t == 2], *ac, 0, 0, 0);                     \
        }                                                                     \
    __builtin_amdgcn_s_barrier();                                             \
  }

  // prologue: stage tile 0 in consumption order P1..P8
  STAGE(0, 0, 0); STAGE(0, 1, 0);   // Ahi.h0, Alo.h0
  STAGE(0, 2, 0); STAGE(0, 3, 0);   // Bhi.h0, Blo.h0
  STAGE(0, 2, 1); STAGE(0, 3, 1);   // Bhi.h1, Blo.h1
  STAGE(0, 0, 1); STAGE(0, 1, 1);   // Ahi.h1, Alo.h1
  asm volatile("s_waitcnt vmcnt(4)" ::: "memory");   // P1..P4 landed
  __builtin_amdgcn_s_barrier();

  int s = 0;
  for (int u = 0; u < NT - 1; ++u, s ^= 1) {
    // ph0 (mh0,nh0): reads P1..P4 data; stage N1,N2; wait -> P5,P6 for ph1
    PH(0, 0, 1, 1, { STAGE(u + 1, 0, 0); STAGE(u + 1, 1, 0); },
       asm volatile("s_waitcnt vmcnt(4)" ::: "memory"));
    // ph1 (mh0,nh1): reads P5,P6; stage N3,N4; wait -> P7,P8 for ph2
    PH(0, 1, 0, 1, { STAGE(u + 1, 2, 0); STAGE(u + 1, 3, 0); },
       asm volatile("s_waitcnt vmcnt(4)" ::: "memory"));
    // ph2 (mh1,nh1): reads P7,P8; stage N5,N6; no wait
    PH(1, 1, 1, 0, { STAGE(u + 1, 2, 1); STAGE(u + 1, 3, 1); }, );
    // ph3 (mh1,nh0): no reads; stage N7,N8; wait -> N1..N4 for next ph0
    PH(1, 0, 0, 0, { STAGE(u + 1, 0, 1); STAGE(u + 1, 1, 1); },
       asm volatile("s_waitcnt vmcnt(4)" ::: "memory"));
  }
  // peeled tile NT-1 (s == 1): no staging; drain
  PH(0, 0, 1, 1, , asm volatile("s_waitcnt vmcnt(2)" ::: "memory"));
  PH(0, 1, 0, 1, , asm volatile("s_waitcnt vmcnt(0)" ::: "memory"));
  PH(1, 1, 1, 0, , );
  PH(1, 0, 0, 0, , );

#undef PH
#undef STAGE

  // ---------- fused quantized-LSTM epilogue ----------
  const int hb = bn * 4 + wc;
  const int h = hb * 16 + lr;
  float bias[4];
#pragma unroll
  for (int g = 0; g < 4; ++g)
    bias[g] = biasC[bn * 256 + ((g >> 1) * 8 + wc * 2 + (g & 1)) * 16 + lr];
#pragma unroll
  for (int mh = 0; mh < 2; ++mh) {
#pragma unroll
    for (int m2 = 0; m2 < 4; ++m2) {
      const int m = mh * 4 + m2;
#pragma unroll
      for (int r = 0; r < 4; ++r) {
        const int row = mbase + mh * 128 + wr * 64 + m2 * 16 + lg * 4 + r;
        const float gi = acc[m][0][r] + bias[0];
        const float gf = acc[m][1][r] + bias[1];
        const float gc = acc[m][2][r] + bias[2];
        const float go = acc[m][3][r] + bias[3];
        const float ig = fq_u(sigm(gi));
        const float fg = fq_u(sigm(gf));
        const float cg = fq_s(tanhf(gc));
        const float og = fq_u(sigm(go));
        const float cxv = cx[(size_t)row * HD + h];
        const float t1 = fq_s(fg * cxv);
        const float t2 = fq_s(ig * cg);
        const float cyv = fq_s((t1 + t2) * 0.5f);
        const float hyv = fq_s(og * fq_s(tanhf(cyv * 2.0f)));
        out[(size_t)row * HD + h] = hyv;
        out[HY_OFF + (size_t)row * HD + h] = cyv;
      }
    }
  }
}

// ---------- launch ----------
extern "C" void kernel_launch(void* const* d_in, const int* in_sizes, int n_in,
                              void* d_out, int out_size, void* d_ws, size_t ws_size,
                              hipStream_t stream) {
  const float* input = (const float*)d_in[0];
  const float* hx    = (const float*)d_in[1];
  const float* cx    = (const float*)d_in[2];
  const float* w_ih  = (const float*)d_in[3];
  const float* w_hh  = (const float*)d_in[4];
  const float* b_ih  = (const float*)d_in[5];
  const float* b_hh  = (const float*)d_in[6];
  const float* n_ih  = (const float*)d_in[7];
  const float* n_hh  = (const float*)d_in[8];
  const float* nb_ih = (const float*)d_in[9];
  const float* nb_hh = (const float*)d_in[10];
  float* out = (float*)d_out;

  char* ws = (char*)d_ws;
  float* maxes = (float*)ws;                                   // 16 B (+pad to 256)
  u16* Xhi = (u16*)(ws + 256);                                 // 16 MB
  u16* Xlo = (u16*)(ws + 256 + 16777216);                      // 16 MB
  u16* Whi = (u16*)(ws + 256 + 2 * 16777216);                  // 4 MB
  u16* Wlo = (u16*)(ws + 256 + 2 * 16777216 + 4194304);        // 4 MB
  float* biasC = (float*)(ws + 256 + 2 * 16777216 + 2 * 4194304); // 8 KB

  hipMemsetAsync(maxes, 0xFF, 16, stream);  // -NaN sentinel; atomic lattice fixes it
  hipLaunchKernelGGL(k_max, dim3(514), dim3(256), 0, stream,
                     w_ih, w_hh, b_ih, b_hh, maxes);
  hipLaunchKernelGGL(k_prep, dim3(2568), dim3(256), 0, stream,
                     input, hx, w_ih, w_hh, n_ih, n_hh, b_ih, b_hh,
                     nb_ih, nb_hh, maxes, Xhi, Xlo, Whi, Wlo, biasC);
  hipLaunchKernelGGL(k_gemm_lstm, dim3(256), dim3(512), 0, stream,
                     Xhi, Xlo, Whi, Wlo, biasC, cx, out);
}

// Round 18
// 122.781 us; speedup vs baseline: 1.2358x; 1.0027x over previous
//
#include <hip/hip_runtime.h>
#include <cstdint>

typedef unsigned short u16;
typedef __bf16 bf16x8 __attribute__((ext_vector_type(8)));
typedef float f32x4 __attribute__((ext_vector_type(4)));

#define NB 8192          // batch rows
#define HD 512           // hidden
#define KD 1024          // IN + H
#define ND 2048          // 4H (physical, column-reordered)
#define HY_OFF (NB * HD) // offset of cy in d_out
#define NT 32            // K-tiles of BK=32

// ---------- helpers ----------
__device__ __forceinline__ u16 f2bf(float f) {
  unsigned u = __float_as_uint(f);
  u += 0x7FFFu + ((u >> 16) & 1u);          // round-to-nearest-even bf16
  return (u16)(u >> 16);
}
__device__ __forceinline__ float bf2f(u16 h) {
  return __uint_as_float(((unsigned)h) << 16);
}
__device__ __forceinline__ void atomicMaxF(float* a, float v) {
  if (v >= 0.f) atomicMax((int*)a, __float_as_int(v));
  else          atomicMin((unsigned int*)a, __float_as_uint(v));
}
__device__ __forceinline__ float fq_u(float x) {           // unsigned 8-bit fake-quant
  float xc = fminf(fmaxf(x, 0.0f), 1.0f);
  return rintf(xc * 256.0f) * (1.0f / 256.0f);
}
__device__ __forceinline__ float fq_s(float x) {           // signed 8-bit fake-quant
  const float lim = 1.0f - 1.0f / 128.0f;
  float xc = fminf(fmaxf(x, -lim), lim);
  return rintf(xc * 128.0f) * (1.0f / 128.0f);
}
__device__ __forceinline__ float sigm(float x) { return 1.0f / (1.0f + expf(-x)); }

__device__ __forceinline__ void gload_lds16(const u16* g, u16* l) {
  __builtin_amdgcn_global_load_lds(
      (const __attribute__((address_space(1))) void*)g,
      (__attribute__((address_space(3))) void*)l, 16, 0, 0);
}

// ---------- k_max: minimal max-reduce (float4) ----------
// blocks [0,256): w_ih ; [256,512): w_hh ; 512: b_ih ; 513: b_hh
__global__ __launch_bounds__(256) void k_max(
    const float* __restrict__ w_ih, const float* __restrict__ w_hh,
    const float* __restrict__ b_ih, const float* __restrict__ b_hh,
    float* __restrict__ maxes) {
  const int bid = blockIdx.x;
  const float4* src; int slot, base4, n4;
  if (bid < 256)      { src = (const float4*)w_ih; slot = 0; base4 = bid * 1024; n4 = 1024; }
  else if (bid < 512) { src = (const float4*)w_hh; slot = 1; base4 = (bid - 256) * 1024; n4 = 1024; }
  else if (bid == 512){ src = (const float4*)b_ih; slot = 2; base4 = 0; n4 = 512; }
  else                { src = (const float4*)b_hh; slot = 3; base4 = 0; n4 = 512; }
  float m = -INFINITY;
  for (int i = threadIdx.x; i < n4; i += 256) {
    float4 v = src[base4 + i];
    m = fmaxf(m, fmaxf(fmaxf(v.x, v.y), fmaxf(v.z, v.w)));
  }
  for (int k = 1; k < 64; k <<= 1) m = fmaxf(m, __shfl_xor(m, k, 64));
  __shared__ float sm[4];
  if ((threadIdx.x & 63) == 0) sm[threadIdx.x >> 6] = m;
  __syncthreads();
  if (threadIdx.x == 0) {
    m = fmaxf(fmaxf(sm[0], sm[1]), fmaxf(sm[2], sm[3]));
    atomicMaxF(&maxes[slot], m);
  }
}

// ---------- fused prep: X-split and W-build INTERLEAVED 4:1, bias tail ----------
// blocks [0,2560): bid%5<4 -> X-split (xi = (bid/5)*4 + bid%5),
//                  bid%5==4 -> W-build (wi = bid/5)  [W overlaps the X stream]
// blocks [2560,2568): bias
// W physical j bits: [10:8]=bn, [7]=nh, [6:5]=wc, [4]=n2, [3:0]=lane
// gate g = 2*nh + n2 ; h-block hb = bn*4 + wc ; logical col = g*512 + hb*16 + j[3:0]
__global__ __launch_bounds__(256) void k_prep(
    const float* __restrict__ input, const float* __restrict__ hx,
    const float* __restrict__ w_ih, const float* __restrict__ w_hh,
    const float* __restrict__ n_ih, const float* __restrict__ n_hh,
    const float* __restrict__ b_ih, const float* __restrict__ b_hh,
    const float* __restrict__ nb_ih, const float* __restrict__ nb_hh,
    const float* __restrict__ maxes,
    u16* __restrict__ Xhi, u16* __restrict__ Xlo,
    u16* __restrict__ Whi, u16* __restrict__ Wlo,
    float* __restrict__ biasC) {
  const int bid = blockIdx.x;
  if (bid < 2560 && (bid % 5) < 4) {
    const int xi = (bid / 5) * 4 + (bid % 5);
    const int total4 = NB * KD / 4;
    for (int e4 = xi * 256 + threadIdx.x; e4 < total4; e4 += 2048 * 256) {
      int row = e4 >> 8;
      int c4  = e4 & 255;
      float4 v = (c4 < 128)
          ? reinterpret_cast<const float4*>(input)[row * 128 + c4]
          : reinterpret_cast<const float4*>(hx)[row * 128 + (c4 - 128)];
      float xs[4] = {v.x, v.y, v.z, v.w};
      ushort4 hi, lo;
      u16 h0 = f2bf(xs[0]); u16 l0 = f2bf(xs[0] - bf2f(h0));
      u16 h1 = f2bf(xs[1]); u16 l1 = f2bf(xs[1] - bf2f(h1));
      u16 h2 = f2bf(xs[2]); u16 l2 = f2bf(xs[2] - bf2f(h2));
      u16 h3 = f2bf(xs[3]); u16 l3 = f2bf(xs[3] - bf2f(h3));
      hi.x = h0; hi.y = h1; hi.z = h2; hi.w = h3;
      lo.x = l0; lo.y = l1; lo.z = l2; lo.w = l3;
      reinterpret_cast<ushort4*>(Xhi)[e4] = hi;
      reinterpret_cast<ushort4*>(Xlo)[e4] = lo;
    }
  } else if (bid < 2560) {
    // one block: 16 physical cols (one lane-group) x 256 k-rows
    __shared__ float nT[256][17];   // padded transpose buffer (17 KB)
    const int w  = bid / 5;         // 0..511
    const int cg = w >> 2, kb = w & 3;
    const int j0 = cg * 16;
    const int g  = ((j0 >> 7) & 1) * 2 + ((j0 >> 4) & 1);
    const int hb = ((j0 >> 8) << 2) | ((j0 >> 5) & 3);
    const int col0 = g * 512 + (hb << 4);
    const int k0 = kb * 256;
    {  // stage noise[k0..k0+256)[col0..col0+16) -> nT, coalesced
      const int cl = threadIdx.x & 15;
      const int kr = threadIdx.x >> 4;
#pragma unroll 4
      for (int i = 0; i < 16; ++i) {
        const int k = k0 + kr + 16 * i;
        nT[kr + 16 * i][cl] = (k < 512) ? n_ih[k * ND + col0 + cl]
                                        : n_hh[(k - 512) * ND + col0 + cl];
      }
    }
    __syncthreads();
    const float s_ih = maxes[0] * 0.1f, s_hh = maxes[1] * 0.1f;
    const int c  = threadIdx.x >> 4;       // col 0..15
    const int kl = threadIdx.x & 15;
    const int colL = col0 + c;
    const int j = j0 + c;
#pragma unroll
    for (int kk = 0; kk < 4; ++kk) {
      const int k = k0 + kk * 64 + kl * 4;
      float4 wv; float s;
      if (k < 512) {
        wv = reinterpret_cast<const float4*>(w_ih)[(colL * 512 + k) >> 2];
        s = s_ih;
      } else {
        wv = reinterpret_cast<const float4*>(w_hh)[(colL * 512 + k - 512) >> 2];
        s = s_hh;
      }
      const int kt = k - k0;
      float xs[4] = {wv.x + nT[kt + 0][c] * s, wv.y + nT[kt + 1][c] * s,
                     wv.z + nT[kt + 2][c] * s, wv.w + nT[kt + 3][c] * s};
      ushort4 hi, lo;
      u16 h0 = f2bf(xs[0]); u16 l0 = f2bf(xs[0] - bf2f(h0));
      u16 h1 = f2bf(xs[1]); u16 l1 = f2bf(xs[1] - bf2f(h1));
      u16 h2 = f2bf(xs[2]); u16 l2 = f2bf(xs[2] - bf2f(h2));
      u16 h3 = f2bf(xs[3]); u16 l3 = f2bf(xs[3] - bf2f(h3));
      hi.x = h0; hi.y = h1; hi.z = h2; hi.w = h3;
      lo.x = l0; lo.y = l1; lo.z = l2; lo.w = l3;
      reinterpret_cast<ushort4*>(Whi)[(j * KD + k) >> 2] = hi;
      reinterpret_cast<ushort4*>(Wlo)[(j * KD + k) >> 2] = lo;
    }
  } else {
    int j = (bid - 2560) * 256 + threadIdx.x;
    if (j < ND) {
      int g  = ((j >> 7) & 1) * 2 + ((j >> 4) & 1);
      int hb = ((j >> 8) << 2) | ((j >> 5) & 3);
      int col = g * 512 + (hb << 4) + (j & 15);
      biasC[j] = b_ih[col] + nb_ih[col] * (maxes[2] * 0.1f)
               + b_hh[col] + nb_hh[col] * (maxes[3] * 0.1f);
    }
  }
}

// ---------- GEMM 256x256-tile, BK=32 unified; SINGLE barrier per phase ----------
// grid 256; 512 threads (8 waves, 2x4); LDS 128 KiB = 2 slots x 4 bufs x 16 KB.
// B-resident XCD map (bn = blk&7). Trailing per-phase barrier removed: stages
// write only the issuing wave's own region (sdst) of the OPPOSITE slot, so no
// intra-tile WAR; the cross-tile WAR (T+1 ph0 stage into slot sT vs slow waves
// reading slot sT) is fenced by ph3(T)'s leading barrier (a wave reaches it
// only after its ph2 reads drained via lgkm before its MFMAs). Data-arrival
// ledger unchanged: vmcnt(4) at ph0/ph1/ph3 guarantees exactly the units the
// next phase reads (verified phase-by-phase). 4 barriers/tile instead of 8.
__global__ __launch_bounds__(512, 2) void k_gemm_lstm(
    const u16* __restrict__ Xhi, const u16* __restrict__ Xlo,
    const u16* __restrict__ Whi, const u16* __restrict__ Wlo,
    const float* __restrict__ biasC, const float* __restrict__ cx,
    float* __restrict__ out) {
  __shared__ u16 L[2][4][8192];   // [slot][Ahi,Alo,Bhi,Blo][128x64]
  const int tid  = threadIdx.x;
  const int lane = tid & 63, wid = tid >> 6;
  const int wr = wid >> 2, wc = wid & 3;       // 2 x 4 waves
  const int lr = lane & 15, lg = lane >> 4;
  // B-resident map: with round-robin blk->XCD dispatch, bn = blk&7 pins one
  // 1 MB W panel per XCD (fits 4 MB L2); bm = blk>>3 streams A via L3.
  const int bn = blockIdx.x & 7;       // 0..7
  const int bm = blockIdx.x >> 3;      // 0..31
  const int mbase = bm * 256, nbase = bn * 256;

  // staging consts: lane l -> ldsrow (l>>3), lds chunk l&7, src chunk (l&7)^(l>>3)
  const int l8 = lane >> 3, l7 = lane & 7;
  const int csrc  = l7 ^ l8;
  const int srow  = wid * 16 + 2 * l8 + (csrc >> 2);  // global row offset in panel
  const int skoff = (csrc & 3) * 8;                   // k offset (u16)
  const int sdst  = wid * 512;                        // + HALF*4096 (u16)

  // frag-read per-thread swizzled offset (u16): row pair + chunk XOR
  const int fro = (lr >> 1) * 64 + ((((lr & 1) << 2) | lg) ^ ((lr >> 1) & 7)) * 8;

  f32x4 acc[8][4] = {};     // [mh*4+m2][gate = 2*nh+n2]
  bf16x8 afr[4][2];         // [m2][hi/lo]
  bf16x8 bfr[2][2][2];      // [nh][n2][hi/lo]

#define STAGE(V, BUF, HALF)                                                   \
  {                                                                           \
    const u16* arr_ = (BUF) == 0 ? Xhi : (BUF) == 1 ? Xlo                     \
                      : (BUF) == 2 ? Whi : Wlo;                               \
    const int gb_ = ((BUF) < 2 ? mbase : nbase) + (HALF) * 128 + srow;        \
    gload_lds16(arr_ + (size_t)gb_ * KD + (V) * 32 + skoff,                   \
                &L[(V) & 1][(BUF)][(HALF) * 4096 + sdst]);                    \
  }

#define PH(MH, NH, LOADA, LOADB, STAGE_CODE, WAIT_CODE)                       \
  {                                                                           \
    if (LOADA) {                                                              \
      _Pragma("unroll") for (int m2 = 0; m2 < 4; ++m2) {                      \
        const int ab = ((MH) * 128 + wr * 64 + m2 * 16) * 32 + fro;           \
        afr[m2][0] = *reinterpret_cast<const bf16x8*>(&L[s][0][ab]);          \
        afr[m2][1] = *reinterpret_cast<const bf16x8*>(&L[s][1][ab]);          \
      }                                                                       \
    }                                                                         \
    if (LOADB) {                                                              \
      _Pragma("unroll") for (int n2 = 0; n2 < 2; ++n2) {                      \
        const int bb = ((NH) * 128 + wc * 32 + n2 * 16) * 32 + fro;           \
        bfr[(NH)][n2][0] = *reinterpret_cast<const bf16x8*>(&L[s][2][bb]);    \
        bfr[(NH)][n2][1] = *reinterpret_cast<const bf16x8*>(&L[s][3][bb]);    \
      }                                                                       \
    }                                                                         \
    STAGE_CODE;                                                               \
    WAIT_CODE;                                                                \
    __builtin_amdgcn_s_barrier();                                             \
    _Pragma("unroll") for (int t = 0; t < 3; ++t)                             \
      _Pragma("unroll") for (int m2 = 0; m2 < 4; ++m2)                        \
        _Pragma("unroll") for (int n2 = 0; n2 < 2; ++n2) {                    \
          f32x4* ac = &acc[(MH) * 4 + m2][(NH) * 2 + n2];                     \
          *ac = __builtin_amdgcn_mfma_f32_16x16x32_bf16(afr[m2][t == 1],      \
                    bfr[(NH)][n2][t == 2], *ac, 0, 0, 0);                     \
        }                                                                     \
  }

  // prologue: stage tile 0 in consumption order P1..P8
  STAGE(0, 0, 0); STAGE(0, 1, 0);   // Ahi.h0, Alo.h0
  STAGE(0, 2, 0); STAGE(0, 3, 0);   // Bhi.h0, Blo.h0
  STAGE(0, 2, 1); STAGE(0, 3, 1);   // Bhi.h1, Blo.h1
  STAGE(0, 0, 1); STAGE(0, 1, 1);   // Ahi.h1, Alo.h1
  asm volatile("s_waitcnt vmcnt(4)" ::: "memory");   // P1..P4 landed
  __builtin_amdgcn_s_barrier();

  int s = 0;
  for (int u = 0; u < NT - 1; ++u, s ^= 1) {
    // ph0 (mh0,nh0): reads P1..P4 data; stage N1,N2; wait -> P5,P6 for ph1
    PH(0, 0, 1, 1, { STAGE(u + 1, 0, 0); STAGE(u + 1, 1, 0); },
       asm volatile("s_waitcnt vmcnt(4)" ::: "memory"));
    // ph1 (mh0,nh1): reads P5,P6; stage N3,N4; wait -> P7,P8 for ph2
    PH(0, 1, 0, 1, { STAGE(u + 1, 2, 0); STAGE(u + 1, 3, 0); },
       asm volatile("s_waitcnt vmcnt(4)" ::: "memory"));
    // ph2 (mh1,nh1): reads P7,P8; stage N5,N6; no wait
    PH(1, 1, 1, 0, { STAGE(u + 1, 2, 1); STAGE(u + 1, 3, 1); }, );
    // ph3 (mh1,nh0): no reads; stage N7,N8; wait -> N1..N4 for next ph0
    PH(1, 0, 0, 0, { STAGE(u + 1, 0, 1); STAGE(u + 1, 1, 1); },
       asm volatile("s_waitcnt vmcnt(4)" ::: "memory"));
  }
  // peeled tile NT-1 (s == 1): no staging; drain
  PH(0, 0, 1, 1, , asm volatile("s_waitcnt vmcnt(2)" ::: "memory"));
  PH(0, 1, 0, 1, , asm volatile("s_waitcnt vmcnt(0)" ::: "memory"));
  PH(1, 1, 1, 0, , );
  PH(1, 0, 0, 0, , );

#undef PH
#undef STAGE

  // ---------- fused quantized-LSTM epilogue ----------
  const int hb = bn * 4 + wc;
  const int h = hb * 16 + lr;
  float bias[4];
#pragma unroll
  for (int g = 0; g < 4; ++g)
    bias[g] = biasC[bn * 256 + ((g >> 1) * 8 + wc * 2 + (g & 1)) * 16 + lr];
#pragma unroll
  for (int mh = 0; mh < 2; ++mh) {
#pragma unroll
    for (int m2 = 0; m2 < 4; ++m2) {
      const int m = mh * 4 + m2;
#pragma unroll
      for (int r = 0; r < 4; ++r) {
        const int row = mbase + mh * 128 + wr * 64 + m2 * 16 + lg * 4 + r;
        const float gi = acc[m][0][r] + bias[0];
        const float gf = acc[m][1][r] + bias[1];
        const float gc = acc[m][2][r] + bias[2];
        const float go = acc[m][3][r] + bias[3];
        const float ig = fq_u(sigm(gi));
        const float fg = fq_u(sigm(gf));
        const float cg = fq_s(tanhf(gc));
        const float og = fq_u(sigm(go));
        const float cxv = cx[(size_t)row * HD + h];
        const float t1 = fq_s(fg * cxv);
        const float t2 = fq_s(ig * cg);
        const float cyv = fq_s((t1 + t2) * 0.5f);
        const float hyv = fq_s(og * fq_s(tanhf(cyv * 2.0f)));
        out[(size_t)row * HD + h] = hyv;
        out[HY_OFF + (size_t)row * HD + h] = cyv;
      }
    }
  }
}

// ---------- launch ----------
extern "C" void kernel_launch(void* const* d_in, const int* in_sizes, int n_in,
                              void* d_out, int out_size, void* d_ws, size_t ws_size,
                              hipStream_t stream) {
  const float* input = (const float*)d_in[0];
  const float* hx    = (const float*)d_in[1];
  const float* cx    = (const float*)d_in[2];
  const float* w_ih  = (const float*)d_in[3];
  const float* w_hh  = (const float*)d_in[4];
  const float* b_ih  = (const float*)d_in[5];
  const float* b_hh  = (const float*)d_in[6];
  const float* n_ih  = (const float*)d_in[7];
  const float* n_hh  = (const float*)d_in[8];
  const float* nb_ih = (const float*)d_in[9];
  const float* nb_hh = (const float*)d_in[10];
  float* out = (float*)d_out;

  char* ws = (char*)d_ws;
  float* maxes = (float*)ws;                                   // 16 B (+pad to 256)
  u16* Xhi = (u16*)(ws + 256);                                 // 16 MB
  u16* Xlo = (u16*)(ws + 256 + 16777216);                      // 16 MB
  u16* Whi = (u16*)(ws + 256 + 2 * 16777216);                  // 4 MB
  u16* Wlo = (u16*)(ws + 256 + 2 * 16777216 + 4194304);        // 4 MB
  float* biasC = (float*)(ws + 256 + 2 * 16777216 + 2 * 4194304); // 8 KB

  hipMemsetAsync(maxes, 0xFF, 16, stream);  // -NaN sentinel; atomic lattice fixes it
  hipLaunchKernelGGL(k_max, dim3(514), dim3(256), 0, stream,
                     w_ih, w_hh, b_ih, b_hh, maxes);
  hipLaunchKernelGGL(k_prep, dim3(2568), dim3(256), 0, stream,
                     input, hx, w_ih, w_hh, n_ih, n_hh, b_ih, b_hh,
                     nb_ih, nb_hh, maxes, Xhi, Xlo, Whi, Wlo, biasC);
  hipLaunchKernelGGL(k_gemm_lstm, dim3(256), dim3(512), 0, stream,
                     Xhi, Xlo, Whi, Wlo, biasC, cx, out);
}